// Round 3
// baseline (2314.212 us; speedup 1.0000x reference)
//
#include <hip/hip_runtime.h>

#define NN 100000
#define HH 64
#define AN 92
#define NSTEP 8
#define NGRP 6250          // NN / 16, exact

__device__ __forceinline__ float sigf(float x) { return 1.0f / (1.0f + __expf(-x)); }
// tanh(x) = 1 - 2/(1+e^{2x}); saturates correctly, no NaN.
__device__ __forceinline__ float tanhfast(float x) { return 1.0f - 2.0f / (1.0f + __expf(2.0f * x)); }
__device__ __forceinline__ float bcast(float v, int k) {
    return __int_as_float(__builtin_amdgcn_readlane(__float_as_int(v), k));
}

// h[n][j] = b[j] + sum_k x[n][k] * W[k][j]   (one wave per node, lane = j)
__global__ __launch_bounds__(256) void k_reduce(const float* __restrict__ x,
                                                const float* __restrict__ W,
                                                const float* __restrict__ b,
                                                float* __restrict__ h) {
    int gid = blockIdx.x * 256 + threadIdx.x;
    int n = gid >> 6, j = gid & 63;
    if (n >= NN) return;
    const float* xr = x + (size_t)n * AN;
    float acc = b[j];
#pragma unroll
    for (int k = 0; k < AN; ++k) acc = fmaf(xr[k], W[k * HH + j], acc);
    h[(size_t)n * HH + j] = acc;
}

// Wc[t][k][r] = sum_q W_g[t][k][q] * w_ih[r][q]    ([8][64][192])
__global__ __launch_bounds__(256) void k_wc(const float* __restrict__ Wg,
                                            const float* __restrict__ w_ih,
                                            float* __restrict__ Wc) {
    __shared__ float wl[192 * 65];
    for (int i = threadIdx.x; i < 192 * 64; i += 256) {
        int r = i >> 6, q = i & 63;
        wl[r * 65 + q] = w_ih[i];
    }
    __syncthreads();
    int gid = blockIdx.x * 256 + threadIdx.x;
    if (gid >= NSTEP * 64 * 192) return;
    int r = gid % 192;
    int k = (gid / 192) & 63;
    int t = gid / (192 * 64);
    const float* wg = Wg + t * 4096 + k * 64;
    float acc = 0.f;
#pragma unroll
    for (int q = 0; q < 64; ++q) acc = fmaf(wg[q], wl[r * 65 + q], acc);
    Wc[gid] = acc;
}

// cur[dst[e]]++  (histogram of in-degrees)
__global__ __launch_bounds__(256) void k_hist(const int* __restrict__ dst, int* __restrict__ cur, int E) {
    int e = blockIdx.x * 256 + threadIdx.x;
    if (e >= E) return;
    atomicAdd(cur + dst[e], 1);
}

// In-place exclusive prefix sum over cur[0..NN). Single block, two-level.
__global__ __launch_bounds__(1024) void k_scan(int* __restrict__ cur) {
    __shared__ int ps[1024];
    const int CH = (NN + 1023) / 1024;
    int t = threadIdx.x;
    int lo = t * CH, hi = min(lo + CH, NN);
    int s = 0;
    for (int i = lo; i < hi; ++i) s += cur[i];
    ps[t] = s;
    __syncthreads();
    for (int off = 1; off < 1024; off <<= 1) {
        int v = (t >= off) ? ps[t - off] : 0;
        __syncthreads();
        ps[t] += v;
        __syncthreads();
    }
    int run = (t == 0) ? 0 : ps[t - 1];
    for (int i = lo; i < hi; ++i) {
        int c = cur[i];
        cur[i] = run;
        run += c;
    }
}

// srt[cur[dst[e]]++] = src[e]   (after: cur[n] = end offset of segment n)
__global__ __launch_bounds__(256) void k_place(const int* __restrict__ src,
                                               const int* __restrict__ dst,
                                               int* __restrict__ cur,
                                               int* __restrict__ srt, int E) {
    int e = blockIdx.x * 256 + threadIdx.x;
    if (e >= E) return;
    int pos = atomicAdd(cur + dst[e], 1);
    srt[pos] = src[e];
}

// S[n][lane] = sum over in-edges of h_old[src][lane]. One wave per node.
// No LDS, tiny VGPR -> full occupancy; 4 partial sums -> 4 outstanding loads.
__global__ __launch_bounds__(256) void k_aggr(const float* __restrict__ h_old,
                                              const int* __restrict__ cur,
                                              const int* __restrict__ srt,
                                              float* __restrict__ S) {
    int gid = blockIdx.x * 256 + threadIdx.x;
    int n = gid >> 6, lane = gid & 63;
    if (n >= NN) return;
    int st = (n == 0) ? 0 : cur[n - 1];
    int en = cur[n];
    float a0 = 0.f, a1 = 0.f, a2 = 0.f, a3 = 0.f;
    int j = st;
    for (; j + 4 <= en; j += 4) {
        int s0 = srt[j], s1 = srt[j + 1], s2 = srt[j + 2], s3 = srt[j + 3];
        a0 += h_old[(size_t)s0 * HH + lane];
        a1 += h_old[(size_t)s1 * HH + lane];
        a2 += h_old[(size_t)s2 * HH + lane];
        a3 += h_old[(size_t)s3 * HH + lane];
    }
    for (; j < en; ++j) a0 += h_old[(size_t)srt[j] * HH + lane];
    S[(size_t)n * HH + lane] = (a0 + a1) + (a2 + a3);
}

// GRU cell: h_new = GRU(S, h_old). 16 nodes per wave, lane = output channel.
// Activation broadcast via v_readlane (no staging LDS); weights in LDS b32,
// stride 193 (conflict-free). h_new may alias S (each wave consumes its own
// S rows before writing).
__global__ __launch_bounds__(1024) void k_gru(const float* __restrict__ S,
                                              const float* __restrict__ h_old,
                                              float* __restrict__ h_new,
                                              const float* __restrict__ Wc_t,
                                              const float* __restrict__ w_hh,
                                              const float* __restrict__ b_ih,
                                              const float* __restrict__ b_hh) {
    __shared__ float wi[64 * 193];   // wi[k*193 + r] = Wc_t[k][r]
    __shared__ float wh[64 * 193];   // wh[k*193 + r] = w_hh[r][k]
    for (int i = threadIdx.x; i < 64 * 192; i += 1024) {
        int k = i / 192, r = i % 192;
        wi[k * 193 + r] = Wc_t[i];
    }
    for (int i = threadIdx.x; i < 192 * 64; i += 1024) {
        int r = i >> 6, k = i & 63;
        wh[k * 193 + r] = w_hh[i];
    }
    __syncthreads();
    int lane = threadIdx.x & 63;
    int wave = threadIdx.x >> 6;                 // 0..15
    int fwid = blockIdx.x + wave * 256;          // flat wave id, 0..4095 (balanced tail)
    float bri = b_ih[lane], bzi = b_ih[64 + lane], bni = b_ih[128 + lane];
    float brh = b_hh[lane], bzh = b_hh[64 + lane], bnh = b_hh[128 + lane];

    for (int g = fwid; g < NGRP; g += 4096) {
        int n0 = g * 16;
        float areg[16], hreg[16];
#pragma unroll
        for (int u = 0; u < 16; ++u) {
            areg[u] = S[(size_t)(n0 + u) * HH + lane];      // coalesced 256B rows
            hreg[u] = h_old[(size_t)(n0 + u) * HH + lane];
        }
        float cr[16], cz[16], ci[16], ch[16];
#pragma unroll
        for (int u = 0; u < 16; ++u) {
            cr[u] = bri + brh; cz[u] = bzi + bzh; ci[u] = bni; ch[u] = bnh;
        }
#pragma unroll 4
        for (int k = 0; k < 64; ++k) {
            float wri = wi[k * 193 + lane];
            float wzi = wi[k * 193 + 64 + lane];
            float wni = wi[k * 193 + 128 + lane];
            float wrh = wh[k * 193 + lane];
            float wzh = wh[k * 193 + 64 + lane];
            float wnh = wh[k * 193 + 128 + lane];
#pragma unroll
            for (int u = 0; u < 16; ++u) {
                float av = bcast(areg[u], k);
                float hv = bcast(hreg[u], k);
                cr[u] = fmaf(av, wri, cr[u]);
                cr[u] = fmaf(hv, wrh, cr[u]);
                cz[u] = fmaf(av, wzi, cz[u]);
                cz[u] = fmaf(hv, wzh, cz[u]);
                ci[u] = fmaf(av, wni, ci[u]);
                ch[u] = fmaf(hv, wnh, ch[u]);
            }
        }
#pragma unroll
        for (int u = 0; u < 16; ++u) {
            float r = sigf(cr[u]);
            float z = sigf(cz[u]);
            float nn2 = tanhfast(fmaf(r, ch[u], ci[u]));
            h_new[(size_t)(n0 + u) * HH + lane] = (1.f - z) * nn2 + z * hreg[u];
        }
    }
}

// out[i] = sigmoid(dot(h[idx[i]], W_lin) + b_lin)
__global__ __launch_bounds__(256) void k_readout(const float* __restrict__ h,
                                                 const int* __restrict__ idx,
                                                 const float* __restrict__ Wl,
                                                 const float* __restrict__ bl,
                                                 float* __restrict__ out, int B) {
    int gid = blockIdx.x * 256 + threadIdx.x;
    int i = gid >> 6, lane = gid & 63;
    if (i >= B) return;
    int n = idx[i];
    float v = h[(size_t)n * HH + lane] * Wl[lane];
#pragma unroll
    for (int off = 32; off > 0; off >>= 1) v += __shfl_xor(v, off, 64);
    if (lane == 0) out[i] = sigf(v + bl[0]);
}

extern "C" void kernel_launch(void* const* d_in, const int* in_sizes, int n_in,
                              void* d_out, int out_size, void* d_ws, size_t ws_size,
                              hipStream_t stream) {
    const float* x     = (const float*)d_in[0];
    const int*   ei    = (const int*)d_in[1];
    const int*   idx   = (const int*)d_in[2];
    const float* W_red = (const float*)d_in[3];
    const float* b_red = (const float*)d_in[4];
    const float* W_g   = (const float*)d_in[5];
    const float* w_ih  = (const float*)d_in[6];
    const float* w_hh  = (const float*)d_in[7];
    const float* b_ih  = (const float*)d_in[8];
    const float* b_hh  = (const float*)d_in[9];
    const float* W_lin = (const float*)d_in[10];
    const float* b_lin = (const float*)d_in[11];
    float* out = (float*)d_out;
    const int E = in_sizes[1] / 2;
    const int B = in_sizes[2];
    const int* src = ei;
    const int* dst = ei + E;

    float* hA = (float*)d_ws;                         // [NN,64] 25.6 MB
    float* hB = hA + (size_t)NN * HH;                 // [NN,64] 25.6 MB
    float* Wc = hB + (size_t)NN * HH;                 // [8,64,192] 393 KB
    int*   cur = (int*)(Wc + (size_t)NSTEP * HH * 3 * HH);  // [NN] 400 KB
    int*   srt = cur + NN;                            // [E] 3.2 MB

    // ---- CSR build (counting sort by dst) ----
    hipMemsetAsync(cur, 0, NN * sizeof(int), stream);
    k_hist<<<(E + 255) / 256, 256, 0, stream>>>(dst, cur, E);
    k_scan<<<1, 1024, 0, stream>>>(cur);
    k_place<<<(E + 255) / 256, 256, 0, stream>>>(src, dst, cur, srt, E);

    // ---- node init + folded weights ----
    k_reduce<<<(NN * 64 + 255) / 256, 256, 0, stream>>>(x, W_red, b_red, hA);
    k_wc<<<(NSTEP * 64 * 192 + 255) / 256, 256, 0, stream>>>(W_g, w_ih, Wc);

    // ---- 8 propagation steps: aggr(h_old -> other buf), gru writes in place over S ----
    for (int t = 0; t < NSTEP; ++t) {
        const float* hold = (t & 1) ? hB : hA;
        float*       Sbuf = (t & 1) ? hA : hB;   // dead buffer becomes S, then h_new
        k_aggr<<<(NN * 64 + 255) / 256, 256, 0, stream>>>(hold, cur, srt, Sbuf);
        k_gru<<<256, 1024, 0, stream>>>(Sbuf, hold, Sbuf,
                                        Wc + (size_t)t * HH * 3 * HH, w_hh, b_ih, b_hh);
    }
    // after 8 steps (even), result is in hA

    k_readout<<<(B * 64 + 255) / 256, 256, 0, stream>>>(hA, idx, W_lin, b_lin, out, B);
}

// Round 4
// 1641.280 us; speedup vs baseline: 1.4100x; 1.4100x over previous
//
#include <hip/hip_runtime.h>
#include <hip/hip_bf16.h>

#define NN 100000
#define HH 64
#define AN 92
#define NSTEP 8
#define NGRP 6250          // NN / 16, exact

typedef float f4v __attribute__((ext_vector_type(4)));
typedef short s8v __attribute__((ext_vector_type(8)));

__device__ __forceinline__ float sigf(float x) { return 1.0f / (1.0f + __expf(-x)); }
// tanh(x) = 1 - 2/(1+e^{2x}); saturates correctly, no NaN.
__device__ __forceinline__ float tanhfast(float x) { return 1.0f - 2.0f / (1.0f + __expf(2.0f * x)); }

__device__ __forceinline__ unsigned short tobf(float x) {
    __hip_bfloat16 b = __float2bfloat16(x);   // RNE
    return __builtin_bit_cast(unsigned short, b);
}
__device__ __forceinline__ float frombf(unsigned short u) {
    return __int_as_float(((unsigned)u) << 16);
}

// h[n][j] = b[j] + sum_k x[n][k]*W[k][j]; writes fp32 h and bf16 shadow hb.
__global__ __launch_bounds__(256) void k_reduce(const float* __restrict__ x,
                                                const float* __restrict__ W,
                                                const float* __restrict__ b,
                                                float* __restrict__ h,
                                                unsigned short* __restrict__ hb) {
    int gid = blockIdx.x * 256 + threadIdx.x;
    int n = gid >> 6, j = gid & 63;
    if (n >= NN) return;
    const float* xr = x + (size_t)n * AN;   // wave-uniform -> scalar loads
    float acc = b[j];
#pragma unroll
    for (int k = 0; k < AN; ++k) acc = fmaf(xr[k], W[k * HH + j], acc);
    h[(size_t)n * HH + j] = acc;
    hb[(size_t)n * HH + j] = tobf(acc);
}

// Packed B-fragment position for mfma_f32_16x16x32_bf16:
// element B[k][r] lives at ((T*2+kh)*64 + lane)*8 + j,
// T=r>>4, kh=k>>5, lane=((k>>3)&3)*16 + (r&15), j=k&7.
__device__ __forceinline__ int packpos(int k, int r) {
    int T = r >> 4, kh = k >> 5;
    int lane = ((k >> 3) & 3) * 16 + (r & 15);
    int j = k & 7;
    return ((T * 2 + kh) * 64 + lane) * 8 + j;
}

// Wc[t][k][r] = sum_q W_g[t][k][q] * w_ih[r][q], emitted bf16 in packed B-frag order.
__global__ __launch_bounds__(256) void k_wc(const float* __restrict__ Wg,
                                            const float* __restrict__ w_ih,
                                            unsigned short* __restrict__ Wcp) {
    __shared__ float wl[192 * 65];
    for (int i = threadIdx.x; i < 192 * 64; i += 256) {
        int r = i >> 6, q = i & 63;
        wl[r * 65 + q] = w_ih[i];
    }
    __syncthreads();
    int gid = blockIdx.x * 256 + threadIdx.x;
    if (gid >= NSTEP * 64 * 192) return;
    int r = gid % 192;
    int k = (gid / 192) & 63;
    int t = gid / (192 * 64);
    const float* wg = Wg + t * 4096 + k * 64;
    float acc = 0.f;
#pragma unroll
    for (int q = 0; q < 64; ++q) acc = fmaf(wg[q], wl[r * 65 + q], acc);
    Wcp[t * 12288 + packpos(k, r)] = tobf(acc);
}

// Whp packed: B[k][r] = w_hh[r][k]  (for gh = h @ w_hh^T)
__global__ __launch_bounds__(256) void k_whp(const float* __restrict__ w_hh,
                                             unsigned short* __restrict__ Whp) {
    int gid = blockIdx.x * 256 + threadIdx.x;
    if (gid >= 192 * 64) return;
    int r = gid >> 6, k = gid & 63;
    Whp[packpos(k, r)] = tobf(w_hh[r * 64 + k]);
}

// cur[dst[e]]++
__global__ __launch_bounds__(256) void k_hist(const int* __restrict__ dst, int* __restrict__ cur, int E) {
    int e = blockIdx.x * 256 + threadIdx.x;
    if (e >= E) return;
    atomicAdd(cur + dst[e], 1);
}

// In-place exclusive prefix sum over cur[0..NN). Single block.
__global__ __launch_bounds__(1024) void k_scan(int* __restrict__ cur) {
    __shared__ int ps[1024];
    const int CH = (NN + 1023) / 1024;
    int t = threadIdx.x;
    int lo = t * CH, hi = min(lo + CH, NN);
    int s = 0;
    for (int i = lo; i < hi; ++i) s += cur[i];
    ps[t] = s;
    __syncthreads();
    for (int off = 1; off < 1024; off <<= 1) {
        int v = (t >= off) ? ps[t - off] : 0;
        __syncthreads();
        ps[t] += v;
        __syncthreads();
    }
    int run = (t == 0) ? 0 : ps[t - 1];
    for (int i = lo; i < hi; ++i) {
        int c = cur[i];
        cur[i] = run;
        run += c;
    }
}

// srt[cur[dst[e]]++] = src[e]
__global__ __launch_bounds__(256) void k_place(const int* __restrict__ src,
                                               const int* __restrict__ dst,
                                               int* __restrict__ cur,
                                               int* __restrict__ srt, int E) {
    int e = blockIdx.x * 256 + threadIdx.x;
    if (e >= E) return;
    int pos = atomicAdd(cur + dst[e], 1);
    srt[pos] = src[e];
}

// Sb[n][lane] = bf16( sum over in-edges of hb[src][lane] ). One wave per node.
__global__ __launch_bounds__(256) void k_aggr(const unsigned short* __restrict__ hb,
                                              const int* __restrict__ cur,
                                              const int* __restrict__ srt,
                                              unsigned short* __restrict__ Sb) {
    int gid = blockIdx.x * 256 + threadIdx.x;
    int n = gid >> 6, lane = gid & 63;
    if (n >= NN) return;
    int st = (n == 0) ? 0 : cur[n - 1];
    int en = cur[n];
    float a0 = 0.f, a1 = 0.f, a2 = 0.f, a3 = 0.f;
    int j = st;
    for (; j + 4 <= en; j += 4) {
        int s0 = srt[j], s1 = srt[j + 1], s2 = srt[j + 2], s3 = srt[j + 3];
        a0 += frombf(hb[(size_t)s0 * HH + lane]);
        a1 += frombf(hb[(size_t)s1 * HH + lane]);
        a2 += frombf(hb[(size_t)s2 * HH + lane]);
        a3 += frombf(hb[(size_t)s3 * HH + lane]);
    }
    for (; j < en; ++j) a0 += frombf(hb[(size_t)srt[j] * HH + lane]);
    Sb[(size_t)n * HH + lane] = tobf((a0 + a1) + (a2 + a3));
}

// convert 8 consecutive fp32 -> bf16x8 fragment
__device__ __forceinline__ s8v cvt8(const float* __restrict__ p) {
    s8v r;
#pragma unroll
    for (int i = 0; i < 8; ++i) r[i] = (short)tobf(p[i]);
    return r;
}

// MFMA GRU: h(inplace fp32) = GRU(Sb, h); also writes bf16 shadow hb.
// One wave per 16 nodes. gi = Sb@Wc + b_ih (bf16 MFMA), gh = h@w_hh^T + b_hh.
// r/z gates: gi+gh accumulated in the SAME tile (legal: r=sig(i_r+h_r)).
__global__ __launch_bounds__(256, 3) void k_gru(const unsigned short* __restrict__ Sb,
                                                float* __restrict__ h,
                                                unsigned short* __restrict__ hb,
                                                const unsigned short* __restrict__ Wcp_t,
                                                const unsigned short* __restrict__ Whp,
                                                const float* __restrict__ b_ih,
                                                const float* __restrict__ b_hh) {
    __shared__ unsigned short wiL[12288];   // 24 KB
    __shared__ unsigned short whL[12288];   // 24 KB
    for (int i = threadIdx.x; i < 12288 / 8; i += 256) {
        ((ulonglong2*)wiL)[i] = ((const ulonglong2*)Wcp_t)[i];
        ((ulonglong2*)whL)[i] = ((const ulonglong2*)Whp)[i];
    }
    __syncthreads();
    const s8v* wiB = (const s8v*)wiL;   // frag (T*2+kh)*64 + lane
    const s8v* whB = (const s8v*)whL;

    int lane = threadIdx.x & 63;
    int wave = threadIdx.x >> 6;
    int quad = lane >> 4, nidx = lane & 15;
    int fwid = blockIdx.x * 4 + wave;
    int tot = gridDim.x * 4;

    // biases (group-invariant): channel c = t*16 + nidx per tile
    float brz[4], bzz[4], bin[4], bhn[4];
#pragma unroll
    for (int t = 0; t < 4; ++t) {
        int c = t * 16 + nidx;
        brz[t] = b_ih[c] + b_hh[c];
        bzz[t] = b_ih[64 + c] + b_hh[64 + c];
        bin[t] = b_ih[128 + c];
        bhn[t] = b_hh[128 + c];
    }

    for (int g = fwid; g < NGRP; g += tot) {
        int n0 = g * 16;
        // A-fragments: row m = nidx, k = quad*8 + j (+32 for kh=1)
        size_t rowoff = (size_t)(n0 + nidx) * HH + quad * 8;
        s8v aS0 = *(const s8v*)(Sb + rowoff);
        s8v aS1 = *(const s8v*)(Sb + rowoff + 32);
        s8v aH0 = cvt8(h + rowoff);
        s8v aH1 = cvt8(h + rowoff + 32);

        f4v accRZ[8], accIN[4], accHN[4];
#pragma unroll
        for (int t = 0; t < 4; ++t) {
            accRZ[t]     = (f4v){brz[t], brz[t], brz[t], brz[t]};
            accRZ[4 + t] = (f4v){bzz[t], bzz[t], bzz[t], bzz[t]};
            accIN[t]     = (f4v){bin[t], bin[t], bin[t], bin[t]};
            accHN[t]     = (f4v){bhn[t], bhn[t], bhn[t], bhn[t]};
        }
#pragma unroll
        for (int t = 0; t < 4; ++t) {
            // r gate: tiles t (cols 0..63)
            accRZ[t] = __builtin_amdgcn_mfma_f32_16x16x32_bf16(aS0, wiB[(t * 2 + 0) * 64 + lane], accRZ[t], 0, 0, 0);
            accRZ[t] = __builtin_amdgcn_mfma_f32_16x16x32_bf16(aS1, wiB[(t * 2 + 1) * 64 + lane], accRZ[t], 0, 0, 0);
            accRZ[t] = __builtin_amdgcn_mfma_f32_16x16x32_bf16(aH0, whB[(t * 2 + 0) * 64 + lane], accRZ[t], 0, 0, 0);
            accRZ[t] = __builtin_amdgcn_mfma_f32_16x16x32_bf16(aH1, whB[(t * 2 + 1) * 64 + lane], accRZ[t], 0, 0, 0);
            // z gate: tiles t+4 (cols 64..127)
            int tz = t + 4;
            accRZ[4 + t] = __builtin_amdgcn_mfma_f32_16x16x32_bf16(aS0, wiB[(tz * 2 + 0) * 64 + lane], accRZ[4 + t], 0, 0, 0);
            accRZ[4 + t] = __builtin_amdgcn_mfma_f32_16x16x32_bf16(aS1, wiB[(tz * 2 + 1) * 64 + lane], accRZ[4 + t], 0, 0, 0);
            accRZ[4 + t] = __builtin_amdgcn_mfma_f32_16x16x32_bf16(aH0, whB[(tz * 2 + 0) * 64 + lane], accRZ[4 + t], 0, 0, 0);
            accRZ[4 + t] = __builtin_amdgcn_mfma_f32_16x16x32_bf16(aH1, whB[(tz * 2 + 1) * 64 + lane], accRZ[4 + t], 0, 0, 0);
            // n gate: tiles t+8 (cols 128..191), gi and gh SEPARATE
            int tn = t + 8;
            accIN[t] = __builtin_amdgcn_mfma_f32_16x16x32_bf16(aS0, wiB[(tn * 2 + 0) * 64 + lane], accIN[t], 0, 0, 0);
            accIN[t] = __builtin_amdgcn_mfma_f32_16x16x32_bf16(aS1, wiB[(tn * 2 + 1) * 64 + lane], accIN[t], 0, 0, 0);
            accHN[t] = __builtin_amdgcn_mfma_f32_16x16x32_bf16(aH0, whB[(tn * 2 + 0) * 64 + lane], accHN[t], 0, 0, 0);
            accHN[t] = __builtin_amdgcn_mfma_f32_16x16x32_bf16(aH1, whB[(tn * 2 + 1) * 64 + lane], accHN[t], 0, 0, 0);
        }
        // epilogue: D row = quad*4+reg (node), col = nidx (channel within tile)
#pragma unroll
        for (int t = 0; t < 4; ++t) {
            int c = t * 16 + nidx;
#pragma unroll
            for (int reg = 0; reg < 4; ++reg) {
                int node = n0 + quad * 4 + reg;
                float rv = sigf(accRZ[t][reg]);
                float zv = sigf(accRZ[4 + t][reg]);
                float nv = tanhfast(fmaf(rv, accHN[t][reg], accIN[t][reg]));
                size_t off = (size_t)node * HH + c;
                float ho = h[off];
                float hnew = fmaf(zv, ho - nv, nv);   // (1-z)n + z h
                h[off] = hnew;
                hb[off] = tobf(hnew);
            }
        }
    }
}

// out[i] = sigmoid(dot(h[idx[i]], W_lin) + b_lin)
__global__ __launch_bounds__(256) void k_readout(const float* __restrict__ h,
                                                 const int* __restrict__ idx,
                                                 const float* __restrict__ Wl,
                                                 const float* __restrict__ bl,
                                                 float* __restrict__ out, int B) {
    int gid = blockIdx.x * 256 + threadIdx.x;
    int i = gid >> 6, lane = gid & 63;
    if (i >= B) return;
    int n = idx[i];
    float v = h[(size_t)n * HH + lane] * Wl[lane];
#pragma unroll
    for (int off = 32; off > 0; off >>= 1) v += __shfl_xor(v, off, 64);
    if (lane == 0) out[i] = sigf(v + bl[0]);
}

extern "C" void kernel_launch(void* const* d_in, const int* in_sizes, int n_in,
                              void* d_out, int out_size, void* d_ws, size_t ws_size,
                              hipStream_t stream) {
    const float* x     = (const float*)d_in[0];
    const int*   ei    = (const int*)d_in[1];
    const int*   idx   = (const int*)d_in[2];
    const float* W_red = (const float*)d_in[3];
    const float* b_red = (const float*)d_in[4];
    const float* W_g   = (const float*)d_in[5];
    const float* w_ih  = (const float*)d_in[6];
    const float* w_hh  = (const float*)d_in[7];
    const float* b_ih  = (const float*)d_in[8];
    const float* b_hh  = (const float*)d_in[9];
    const float* W_lin = (const float*)d_in[10];
    const float* b_lin = (const float*)d_in[11];
    float* out = (float*)d_out;
    const int E = in_sizes[1] / 2;
    const int B = in_sizes[2];
    const int* src = ei;
    const int* dst = ei + E;

    float*          h   = (float*)d_ws;                       // [NN,64] fp32   25.6 MB
    unsigned short* hb  = (unsigned short*)(h + (size_t)NN * HH);       // bf16 12.8 MB
    unsigned short* Sb  = hb + (size_t)NN * HH;               // bf16 12.8 MB
    unsigned short* Wcp = Sb + (size_t)NN * HH;               // [8][12288] bf16 196 KB
    unsigned short* Whp = Wcp + (size_t)NSTEP * 12288;        // [12288] bf16 24 KB
    int*            cur = (int*)(Whp + 12288);                // [NN]
    int*            srt = cur + NN;                           // [E]

    // ---- CSR build (counting sort by dst) ----
    hipMemsetAsync(cur, 0, NN * sizeof(int), stream);
    k_hist<<<(E + 255) / 256, 256, 0, stream>>>(dst, cur, E);
    k_scan<<<1, 1024, 0, stream>>>(cur);
    k_place<<<(E + 255) / 256, 256, 0, stream>>>(src, dst, cur, srt, E);

    // ---- node init + packed weights ----
    k_reduce<<<(NN * 64 + 255) / 256, 256, 0, stream>>>(x, W_red, b_red, h, hb);
    k_wc<<<(NSTEP * 64 * 192 + 255) / 256, 256, 0, stream>>>(W_g, w_ih, Wcp);
    k_whp<<<(192 * 64 + 255) / 256, 256, 0, stream>>>(w_hh, Whp);

    // ---- 8 propagation steps ----
    for (int t = 0; t < NSTEP; ++t) {
        k_aggr<<<(NN * 64 + 255) / 256, 256, 0, stream>>>(hb, cur, srt, Sb);
        k_gru<<<782, 256, 0, stream>>>(Sb, h, hb, Wcp + (size_t)t * 12288, Whp,
                                       b_ih, b_hh);
    }

    k_readout<<<(B * 64 + 255) / 256, 256, 0, stream>>>(h, idx, W_lin, b_lin, out, B);
}

// Round 5
// 1464.116 us; speedup vs baseline: 1.5806x; 1.1210x over previous
//
#include <hip/hip_runtime.h>
#include <hip/hip_bf16.h>

#define NN 100000
#define HH 64
#define AN 92
#define NSTEP 8
#define NGRP 6250          // NN / 16, exact
#define NB 391             // ceil(NN / 256)

typedef float f4v __attribute__((ext_vector_type(4)));
typedef short s8v __attribute__((ext_vector_type(8)));

__device__ __forceinline__ float sigf(float x) { return 1.0f / (1.0f + __expf(-x)); }
// tanh(x) = 1 - 2/(1+e^{2x}); saturates correctly, no NaN.
__device__ __forceinline__ float tanhfast(float x) { return 1.0f - 2.0f / (1.0f + __expf(2.0f * x)); }

__device__ __forceinline__ unsigned short tobf(float x) {
    __hip_bfloat16 b = __float2bfloat16(x);   // RNE
    return __builtin_bit_cast(unsigned short, b);
}
__device__ __forceinline__ float frombf(unsigned short u) {
    return __int_as_float(((unsigned)u) << 16);
}

// h[n][j] = b[j] + sum_k x[n][k]*W[k][j]; writes fp32 h and bf16 shadow hb.
__global__ __launch_bounds__(256) void k_reduce(const float* __restrict__ x,
                                                const float* __restrict__ W,
                                                const float* __restrict__ b,
                                                float* __restrict__ h,
                                                unsigned short* __restrict__ hb) {
    int gid = blockIdx.x * 256 + threadIdx.x;
    int n = gid >> 6, j = gid & 63;
    if (n >= NN) return;
    const float* xr = x + (size_t)n * AN;   // wave-uniform -> scalar loads
    float acc = b[j];
#pragma unroll
    for (int k = 0; k < AN; ++k) acc = fmaf(xr[k], W[k * HH + j], acc);
    h[(size_t)n * HH + j] = acc;
    hb[(size_t)n * HH + j] = tobf(acc);
}

// Packed B-fragment position for mfma_f32_16x16x32_bf16:
// element B[k][r] lives at ((T*2+kh)*64 + lane)*8 + j,
// T=r>>4, kh=k>>5, lane=((k>>3)&3)*16 + (r&15), j=k&7.
__device__ __forceinline__ int packpos(int k, int r) {
    int T = r >> 4, kh = k >> 5;
    int lane = ((k >> 3) & 3) * 16 + (r & 15);
    int j = k & 7;
    return ((T * 2 + kh) * 64 + lane) * 8 + j;
}

// Wc[t][k][r] = sum_q W_g[t][k][q] * w_ih[r][q], emitted bf16 in packed B-frag order.
__global__ __launch_bounds__(256) void k_wc(const float* __restrict__ Wg,
                                            const float* __restrict__ w_ih,
                                            unsigned short* __restrict__ Wcp) {
    __shared__ float wl[192 * 65];
    for (int i = threadIdx.x; i < 192 * 64; i += 256) {
        int r = i >> 6, q = i & 63;
        wl[r * 65 + q] = w_ih[i];
    }
    __syncthreads();
    int gid = blockIdx.x * 256 + threadIdx.x;
    if (gid >= NSTEP * 64 * 192) return;
    int r = gid % 192;
    int k = (gid / 192) & 63;
    int t = gid / (192 * 64);
    const float* wg = Wg + t * 4096 + k * 64;
    float acc = 0.f;
#pragma unroll
    for (int q = 0; q < 64; ++q) acc = fmaf(wg[q], wl[r * 65 + q], acc);
    Wcp[t * 12288 + packpos(k, r)] = tobf(acc);
}

// Whp packed: B[k][r] = w_hh[r][k]  (for gh = h @ w_hh^T)
__global__ __launch_bounds__(256) void k_whp(const float* __restrict__ w_hh,
                                             unsigned short* __restrict__ Whp) {
    int gid = blockIdx.x * 256 + threadIdx.x;
    if (gid >= 192 * 64) return;
    int r = gid >> 6, k = gid & 63;
    Whp[packpos(k, r)] = tobf(w_hh[r * 64 + k]);
}

// cur[dst[e]]++
__global__ __launch_bounds__(256) void k_hist(const int* __restrict__ dst, int* __restrict__ cur, int E) {
    int e = blockIdx.x * 256 + threadIdx.x;
    if (e >= E) return;
    atomicAdd(cur + dst[e], 1);
}

// ---- parallel 3-phase exclusive scan of cur[0..NN) ----
// phase 1: per-block sums
__global__ __launch_bounds__(256) void k_scan1(const int* __restrict__ cur, int* __restrict__ bsum) {
    __shared__ int ws[4];
    int gid = blockIdx.x * 256 + threadIdx.x;
    int lane = threadIdx.x & 63, wave = threadIdx.x >> 6;
    int v = (gid < NN) ? cur[gid] : 0;
#pragma unroll
    for (int off = 32; off > 0; off >>= 1) v += __shfl_xor(v, off, 64);
    if (lane == 0) ws[wave] = v;
    __syncthreads();
    if (threadIdx.x == 0) bsum[blockIdx.x] = ws[0] + ws[1] + ws[2] + ws[3];
}

// phase 2: exclusive scan of NB block sums (single small block)
__global__ __launch_bounds__(512) void k_scan2(int* __restrict__ bsum) {
    __shared__ int s[512];
    int t = threadIdx.x;
    int v = (t < NB) ? bsum[t] : 0;
    s[t] = v;
    __syncthreads();
    for (int off = 1; off < 512; off <<= 1) {
        int w = (t >= off) ? s[t - off] : 0;
        __syncthreads();
        s[t] += w;
        __syncthreads();
    }
    if (t < NB) bsum[t] = s[t] - v;   // exclusive
}

// phase 3: in-block exclusive scan + block offset, in place
__global__ __launch_bounds__(256) void k_scan3(int* __restrict__ cur, const int* __restrict__ bsum) {
    __shared__ int ws[4];
    int gid = blockIdx.x * 256 + threadIdx.x;
    int lane = threadIdx.x & 63, wave = threadIdx.x >> 6;
    int orig = (gid < NN) ? cur[gid] : 0;
    int v = orig;
#pragma unroll
    for (int off = 1; off < 64; off <<= 1) {
        int w = __shfl_up(v, off, 64);
        if (lane >= off) v += w;
    }
    if (lane == 63) ws[wave] = v;
    __syncthreads();
    int woff = 0;
    for (int w = 0; w < 4; ++w) woff += (w < wave) ? ws[w] : 0;
    if (gid < NN) cur[gid] = v - orig + woff + bsum[blockIdx.x];
}

// srt[cur[dst[e]]++] = src[e]   (after: cur[n] = end offset of segment n)
__global__ __launch_bounds__(256) void k_place(const int* __restrict__ src,
                                               const int* __restrict__ dst,
                                               int* __restrict__ cur,
                                               int* __restrict__ srt, int E) {
    int e = blockIdx.x * 256 + threadIdx.x;
    if (e >= E) return;
    int pos = atomicAdd(cur + dst[e], 1);
    srt[pos] = src[e];
}

// Sb[n][:] = bf16( sum over in-edges of hb[src][:] ). One wave per node;
// lane loads 4B (2 channels), half-wave 0 = edge j, half-wave 1 = edge j+1.
__global__ __launch_bounds__(256) void k_aggr(const unsigned short* __restrict__ hb,
                                              const int* __restrict__ cur,
                                              const int* __restrict__ srt,
                                              unsigned short* __restrict__ Sb) {
    int gid = blockIdx.x * 256 + threadIdx.x;
    int n = gid >> 6, lane = gid & 63;
    if (n >= NN) return;
    int half = lane >> 5;          // which edge of the pair
    int ci = lane & 31;            // uint index within row (2 channels)
    int st = (n == 0) ? 0 : cur[n - 1];
    int en = cur[n];
    float a0 = 0.f, b0 = 0.f, a1 = 0.f, b1 = 0.f;
    int j = st;
    for (; j + 4 <= en; j += 4) {
        int s0 = srt[j + half];
        int s1 = srt[j + 2 + half];
        unsigned u0 = *(const unsigned*)(hb + (size_t)s0 * HH + ci * 2);
        unsigned u1 = *(const unsigned*)(hb + (size_t)s1 * HH + ci * 2);
        a0 += frombf((unsigned short)u0);
        b0 += frombf((unsigned short)(u0 >> 16));
        a1 += frombf((unsigned short)u1);
        b1 += frombf((unsigned short)(u1 >> 16));
    }
    for (; j < en; j += 2) {
        int jj = j + half;
        if (jj < en) {
            unsigned u = *(const unsigned*)(hb + (size_t)srt[jj] * HH + ci * 2);
            a0 += frombf((unsigned short)u);
            b0 += frombf((unsigned short)(u >> 16));
        }
    }
    a0 += a1; b0 += b1;
    a0 += __shfl_xor(a0, 32, 64);
    b0 += __shfl_xor(b0, 32, 64);
    if (half == 0) {
        unsigned o = (unsigned)tobf(a0) | ((unsigned)tobf(b0) << 16);
        *(unsigned*)(Sb + (size_t)n * HH + ci * 2) = o;
    }
}

// convert 8 consecutive fp32 -> bf16x8 fragment
__device__ __forceinline__ s8v cvt8(const float* __restrict__ p) {
    s8v r;
#pragma unroll
    for (int i = 0; i < 8; ++i) r[i] = (short)tobf(p[i]);
    return r;
}

// MFMA GRU: h(inplace fp32) = GRU(Sb, h); also writes bf16 shadow hb.
__global__ __launch_bounds__(256, 3) void k_gru(const unsigned short* __restrict__ Sb,
                                                float* __restrict__ h,
                                                unsigned short* __restrict__ hb,
                                                const unsigned short* __restrict__ Wcp_t,
                                                const unsigned short* __restrict__ Whp,
                                                const float* __restrict__ b_ih,
                                                const float* __restrict__ b_hh) {
    __shared__ unsigned short wiL[12288];   // 24 KB
    __shared__ unsigned short whL[12288];   // 24 KB
    for (int i = threadIdx.x; i < 12288 / 8; i += 256) {
        ((ulonglong2*)wiL)[i] = ((const ulonglong2*)Wcp_t)[i];
        ((ulonglong2*)whL)[i] = ((const ulonglong2*)Whp)[i];
    }
    __syncthreads();
    const s8v* wiB = (const s8v*)wiL;
    const s8v* whB = (const s8v*)whL;

    int lane = threadIdx.x & 63;
    int wave = threadIdx.x >> 6;
    int quad = lane >> 4, nidx = lane & 15;
    int fwid = blockIdx.x * 4 + wave;
    int tot = gridDim.x * 4;

    float brz[4], bzz[4], bin[4], bhn[4];
#pragma unroll
    for (int t = 0; t < 4; ++t) {
        int c = t * 16 + nidx;
        brz[t] = b_ih[c] + b_hh[c];
        bzz[t] = b_ih[64 + c] + b_hh[64 + c];
        bin[t] = b_ih[128 + c];
        bhn[t] = b_hh[128 + c];
    }

    for (int g = fwid; g < NGRP; g += tot) {
        int n0 = g * 16;
        size_t rowoff = (size_t)(n0 + nidx) * HH + quad * 8;
        s8v aS0 = *(const s8v*)(Sb + rowoff);
        s8v aS1 = *(const s8v*)(Sb + rowoff + 32);
        s8v aH0 = cvt8(h + rowoff);
        s8v aH1 = cvt8(h + rowoff + 32);

        f4v accRZ[8], accIN[4], accHN[4];
#pragma unroll
        for (int t = 0; t < 4; ++t) {
            accRZ[t]     = (f4v){brz[t], brz[t], brz[t], brz[t]};
            accRZ[4 + t] = (f4v){bzz[t], bzz[t], bzz[t], bzz[t]};
            accIN[t]     = (f4v){bin[t], bin[t], bin[t], bin[t]};
            accHN[t]     = (f4v){bhn[t], bhn[t], bhn[t], bhn[t]};
        }
#pragma unroll
        for (int t = 0; t < 4; ++t) {
            accRZ[t] = __builtin_amdgcn_mfma_f32_16x16x32_bf16(aS0, wiB[(t * 2 + 0) * 64 + lane], accRZ[t], 0, 0, 0);
            accRZ[t] = __builtin_amdgcn_mfma_f32_16x16x32_bf16(aS1, wiB[(t * 2 + 1) * 64 + lane], accRZ[t], 0, 0, 0);
            accRZ[t] = __builtin_amdgcn_mfma_f32_16x16x32_bf16(aH0, whB[(t * 2 + 0) * 64 + lane], accRZ[t], 0, 0, 0);
            accRZ[t] = __builtin_amdgcn_mfma_f32_16x16x32_bf16(aH1, whB[(t * 2 + 1) * 64 + lane], accRZ[t], 0, 0, 0);
            int tz = t + 4;
            accRZ[4 + t] = __builtin_amdgcn_mfma_f32_16x16x32_bf16(aS0, wiB[(tz * 2 + 0) * 64 + lane], accRZ[4 + t], 0, 0, 0);
            accRZ[4 + t] = __builtin_amdgcn_mfma_f32_16x16x32_bf16(aS1, wiB[(tz * 2 + 1) * 64 + lane], accRZ[4 + t], 0, 0, 0);
            accRZ[4 + t] = __builtin_amdgcn_mfma_f32_16x16x32_bf16(aH0, whB[(tz * 2 + 0) * 64 + lane], accRZ[4 + t], 0, 0, 0);
            accRZ[4 + t] = __builtin_amdgcn_mfma_f32_16x16x32_bf16(aH1, whB[(tz * 2 + 1) * 64 + lane], accRZ[4 + t], 0, 0, 0);
            int tn = t + 8;
            accIN[t] = __builtin_amdgcn_mfma_f32_16x16x32_bf16(aS0, wiB[(tn * 2 + 0) * 64 + lane], accIN[t], 0, 0, 0);
            accIN[t] = __builtin_amdgcn_mfma_f32_16x16x32_bf16(aS1, wiB[(tn * 2 + 1) * 64 + lane], accIN[t], 0, 0, 0);
            accHN[t] = __builtin_amdgcn_mfma_f32_16x16x32_bf16(aH0, whB[(tn * 2 + 0) * 64 + lane], accHN[t], 0, 0, 0);
            accHN[t] = __builtin_amdgcn_mfma_f32_16x16x32_bf16(aH1, whB[(tn * 2 + 1) * 64 + lane], accHN[t], 0, 0, 0);
        }
#pragma unroll
        for (int t = 0; t < 4; ++t) {
            int c = t * 16 + nidx;
#pragma unroll
            for (int reg = 0; reg < 4; ++reg) {
                int node = n0 + quad * 4 + reg;
                float rv = sigf(accRZ[t][reg]);
                float zv = sigf(accRZ[4 + t][reg]);
                float nv = tanhfast(fmaf(rv, accHN[t][reg], accIN[t][reg]));
                size_t off = (size_t)node * HH + c;
                float ho = h[off];
                float hnew = fmaf(zv, ho - nv, nv);   // (1-z)n + z h
                h[off] = hnew;
                hb[off] = tobf(hnew);
            }
        }
    }
}

// out[i] = sigmoid(dot(h[idx[i]], W_lin) + b_lin)
__global__ __launch_bounds__(256) void k_readout(const float* __restrict__ h,
                                                 const int* __restrict__ idx,
                                                 const float* __restrict__ Wl,
                                                 const float* __restrict__ bl,
                                                 float* __restrict__ out, int B) {
    int gid = blockIdx.x * 256 + threadIdx.x;
    int i = gid >> 6, lane = gid & 63;
    if (i >= B) return;
    int n = idx[i];
    float v = h[(size_t)n * HH + lane] * Wl[lane];
#pragma unroll
    for (int off = 32; off > 0; off >>= 1) v += __shfl_xor(v, off, 64);
    if (lane == 0) out[i] = sigf(v + bl[0]);
}

extern "C" void kernel_launch(void* const* d_in, const int* in_sizes, int n_in,
                              void* d_out, int out_size, void* d_ws, size_t ws_size,
                              hipStream_t stream) {
    const float* x     = (const float*)d_in[0];
    const int*   ei    = (const int*)d_in[1];
    const int*   idx   = (const int*)d_in[2];
    const float* W_red = (const float*)d_in[3];
    const float* b_red = (const float*)d_in[4];
    const float* W_g   = (const float*)d_in[5];
    const float* w_ih  = (const float*)d_in[6];
    const float* w_hh  = (const float*)d_in[7];
    const float* b_ih  = (const float*)d_in[8];
    const float* b_hh  = (const float*)d_in[9];
    const float* W_lin = (const float*)d_in[10];
    const float* b_lin = (const float*)d_in[11];
    float* out = (float*)d_out;
    const int E = in_sizes[1] / 2;
    const int B = in_sizes[2];
    const int* src = ei;
    const int* dst = ei + E;

    float*          h   = (float*)d_ws;                          // [NN,64] fp32
    unsigned short* hb  = (unsigned short*)(h + (size_t)NN * HH);
    unsigned short* Sb  = hb + (size_t)NN * HH;
    unsigned short* Wcp = Sb + (size_t)NN * HH;
    unsigned short* Whp = Wcp + (size_t)NSTEP * 12288;
    int*            cur = (int*)(Whp + 12288);
    int*            srt = cur + NN;
    int*            bsum = srt + E;                               // [NB]

    // ---- CSR build (counting sort by dst, parallel scan) ----
    hipMemsetAsync(cur, 0, NN * sizeof(int), stream);
    k_hist<<<(E + 255) / 256, 256, 0, stream>>>(dst, cur, E);
    k_scan1<<<NB, 256, 0, stream>>>(cur, bsum);
    k_scan2<<<1, 512, 0, stream>>>(bsum);
    k_scan3<<<NB, 256, 0, stream>>>(cur, bsum);
    k_place<<<(E + 255) / 256, 256, 0, stream>>>(src, dst, cur, srt, E);

    // ---- node init + packed weights ----
    k_reduce<<<(NN * 64 + 255) / 256, 256, 0, stream>>>(x, W_red, b_red, h, hb);
    k_wc<<<(NSTEP * 64 * 192 + 255) / 256, 256, 0, stream>>>(W_g, w_ih, Wcp);
    k_whp<<<(192 * 64 + 255) / 256, 256, 0, stream>>>(w_hh, Whp);

    // ---- 8 propagation steps ----
    for (int t = 0; t < NSTEP; ++t) {
        k_aggr<<<(NN * 64 + 255) / 256, 256, 0, stream>>>(hb, cur, srt, Sb);
        k_gru<<<782, 256, 0, stream>>>(Sb, h, hb, Wcp + (size_t)t * 12288, Whp,
                                       b_ih, b_hh);
    }

    k_readout<<<(B * 64 + 255) / 256, 256, 0, stream>>>(h, idx, W_lin, b_lin, out, B);
}

// Round 6
// 1299.757 us; speedup vs baseline: 1.7805x; 1.1265x over previous
//
#include <hip/hip_runtime.h>
#include <hip/hip_bf16.h>

#define NN 100000
#define HH 64
#define AN 92
#define NSTEP 8
#define NGRP 6250          // NN / 16, exact
#define NB 391             // ceil(NN / 256)

typedef float f4v __attribute__((ext_vector_type(4)));
typedef short s8v __attribute__((ext_vector_type(8)));

__device__ __forceinline__ float sigf(float x) { return 1.0f / (1.0f + __expf(-x)); }
// tanh(x) = 1 - 2/(1+e^{2x}); saturates correctly, no NaN.
__device__ __forceinline__ float tanhfast(float x) { return 1.0f - 2.0f / (1.0f + __expf(2.0f * x)); }

__device__ __forceinline__ unsigned short tobf(float x) {
    __hip_bfloat16 b = __float2bfloat16(x);   // RNE
    return __builtin_bit_cast(unsigned short, b);
}
__device__ __forceinline__ float frombf(unsigned short u) {
    return __int_as_float(((unsigned)u) << 16);
}

// h = x @ W_red + b. 16 nodes/block; x rows staged to LDS coalesced;
// compute via LDS broadcasts. Writes fp32 h and bf16 shadow hb.
__global__ __launch_bounds__(256) void k_reduce(const float* __restrict__ x,
                                                const float* __restrict__ W,
                                                const float* __restrict__ b,
                                                float* __restrict__ h,
                                                unsigned short* __restrict__ hb) {
    __shared__ float xl[16][96];      // k padded to 96, pads zeroed
    __shared__ float wl[96 * 64];     // wl[k*64+j] = W[k][j]; k=92..95 zeroed
    int tid = threadIdx.x;
    int n0 = blockIdx.x * 16;         // NN % 16 == 0 -> no tail
    // stage x: 16 rows are contiguous in global -> perfectly coalesced
    for (int i = tid; i < 16 * AN; i += 256)
        xl[i / AN][i % AN] = x[(size_t)n0 * AN + i];
    if (tid < 64) xl[tid >> 2][AN + (tid & 3)] = 0.f;          // zero x pads
    for (int i = tid; i < AN * 64; i += 256) wl[i] = W[i];
    wl[AN * 64 + tid] = 0.f;                                    // zero k=92..95 rows (4*64=256)
    __syncthreads();
    int lane = tid & 63, wave = tid >> 6;
    float a[4];
    float bj = b[lane];
#pragma unroll
    for (int u = 0; u < 4; ++u) a[u] = bj;
#pragma unroll
    for (int k4 = 0; k4 < 96; k4 += 4) {
        float4 xv[4];
#pragma unroll
        for (int u = 0; u < 4; ++u) xv[u] = *(const float4*)&xl[wave * 4 + u][k4];   // broadcast
#pragma unroll
        for (int kk = 0; kk < 4; ++kk) {
            float wv = wl[(k4 + kk) * 64 + lane];   // 2-way bank alias: free
            a[0] = fmaf(((const float*)&xv[0])[kk], wv, a[0]);
            a[1] = fmaf(((const float*)&xv[1])[kk], wv, a[1]);
            a[2] = fmaf(((const float*)&xv[2])[kk], wv, a[2]);
            a[3] = fmaf(((const float*)&xv[3])[kk], wv, a[3]);
        }
    }
#pragma unroll
    for (int u = 0; u < 4; ++u) {
        int n = n0 + wave * 4 + u;
        h[(size_t)n * HH + lane] = a[u];
        hb[(size_t)n * HH + lane] = tobf(a[u]);
    }
}

// Packed B-fragment position for mfma_f32_16x16x32_bf16:
// element B[k][r] lives at ((T*2+kh)*64 + lane)*8 + j,
// T=r>>4, kh=k>>5, lane=((k>>3)&3)*16 + (r&15), j=k&7.
__device__ __forceinline__ int packpos(int k, int r) {
    int T = r >> 4, kh = k >> 5;
    int lane = ((k >> 3) & 3) * 16 + (r & 15);
    int j = k & 7;
    return ((T * 2 + kh) * 64 + lane) * 8 + j;
}

// Wc[t][k][r] = sum_q W_g[t][k][q] * w_ih[r][q], emitted bf16 in packed B-frag order.
__global__ __launch_bounds__(256) void k_wc(const float* __restrict__ Wg,
                                            const float* __restrict__ w_ih,
                                            unsigned short* __restrict__ Wcp) {
    __shared__ float wl[192 * 65];
    for (int i = threadIdx.x; i < 192 * 64; i += 256) {
        int r = i >> 6, q = i & 63;
        wl[r * 65 + q] = w_ih[i];
    }
    __syncthreads();
    int gid = blockIdx.x * 256 + threadIdx.x;
    if (gid >= NSTEP * 64 * 192) return;
    int r = gid % 192;
    int k = (gid / 192) & 63;
    int t = gid / (192 * 64);
    const float* wg = Wg + t * 4096 + k * 64;
    float acc = 0.f;
#pragma unroll
    for (int q = 0; q < 64; ++q) acc = fmaf(wg[q], wl[r * 65 + q], acc);
    Wcp[t * 12288 + packpos(k, r)] = tobf(acc);
}

// Whp packed: B[k][r] = w_hh[r][k]  (for gh = h @ w_hh^T)
__global__ __launch_bounds__(256) void k_whp(const float* __restrict__ w_hh,
                                             unsigned short* __restrict__ Whp) {
    int gid = blockIdx.x * 256 + threadIdx.x;
    if (gid >= 192 * 64) return;
    int r = gid >> 6, k = gid & 63;
    Whp[packpos(k, r)] = tobf(w_hh[r * 64 + k]);
}

// cur[dst[e]]++
__global__ __launch_bounds__(256) void k_hist(const int* __restrict__ dst, int* __restrict__ cur, int E) {
    int e = blockIdx.x * 256 + threadIdx.x;
    if (e >= E) return;
    atomicAdd(cur + dst[e], 1);
}

// ---- parallel 3-phase exclusive scan of cur[0..NN) ----
__global__ __launch_bounds__(256) void k_scan1(const int* __restrict__ cur, int* __restrict__ bsum) {
    __shared__ int ws[4];
    int gid = blockIdx.x * 256 + threadIdx.x;
    int lane = threadIdx.x & 63, wave = threadIdx.x >> 6;
    int v = (gid < NN) ? cur[gid] : 0;
#pragma unroll
    for (int off = 32; off > 0; off >>= 1) v += __shfl_xor(v, off, 64);
    if (lane == 0) ws[wave] = v;
    __syncthreads();
    if (threadIdx.x == 0) bsum[blockIdx.x] = ws[0] + ws[1] + ws[2] + ws[3];
}

__global__ __launch_bounds__(512) void k_scan2(int* __restrict__ bsum) {
    __shared__ int s[512];
    int t = threadIdx.x;
    int v = (t < NB) ? bsum[t] : 0;
    s[t] = v;
    __syncthreads();
    for (int off = 1; off < 512; off <<= 1) {
        int w = (t >= off) ? s[t - off] : 0;
        __syncthreads();
        s[t] += w;
        __syncthreads();
    }
    if (t < NB) bsum[t] = s[t] - v;   // exclusive
}

__global__ __launch_bounds__(256) void k_scan3(int* __restrict__ cur, const int* __restrict__ bsum) {
    __shared__ int ws[4];
    int gid = blockIdx.x * 256 + threadIdx.x;
    int lane = threadIdx.x & 63, wave = threadIdx.x >> 6;
    int orig = (gid < NN) ? cur[gid] : 0;
    int v = orig;
#pragma unroll
    for (int off = 1; off < 64; off <<= 1) {
        int w = __shfl_up(v, off, 64);
        if (lane >= off) v += w;
    }
    if (lane == 63) ws[wave] = v;
    __syncthreads();
    int woff = 0;
    for (int w = 0; w < 4; ++w) woff += (w < wave) ? ws[w] : 0;
    if (gid < NN) cur[gid] = v - orig + woff + bsum[blockIdx.x];
}

// srt[cur[dst[e]]++] = src[e]   (after: cur[n] = end offset of segment n)
__global__ __launch_bounds__(256) void k_place(const int* __restrict__ src,
                                               const int* __restrict__ dst,
                                               int* __restrict__ cur,
                                               int* __restrict__ srt, int E) {
    int e = blockIdx.x * 256 + threadIdx.x;
    if (e >= E) return;
    int pos = atomicAdd(cur + dst[e], 1);
    srt[pos] = src[e];
}

// Sb[n][:] = bf16( sum over in-edges of hb[src][:] ).
// 2 nodes per wave (half-wave = full 128B row); 4-deep edge unroll
// -> 4 independent gathers in flight per half-wave.
__global__ __launch_bounds__(256) void k_aggr(const unsigned short* __restrict__ hb,
                                              const int* __restrict__ cur,
                                              const int* __restrict__ srt,
                                              unsigned short* __restrict__ Sb) {
    int gid = blockIdx.x * 256 + threadIdx.x;
    int wid = gid >> 6;
    int lane = threadIdx.x & 63;
    int half = lane >> 5;           // which node of the pair
    int ci = lane & 31;             // uint index within row (2 channels)
    int n = wid * 2 + half;
    if (n >= NN) return;
    int st = (n == 0) ? 0 : cur[n - 1];
    int en = cur[n];
    float a0 = 0.f, b0 = 0.f, a1 = 0.f, b1 = 0.f;
    float a2 = 0.f, b2 = 0.f, a3 = 0.f, b3 = 0.f;
    int j = st;
    for (; j + 4 <= en; j += 4) {
        int s0 = srt[j], s1 = srt[j + 1], s2 = srt[j + 2], s3 = srt[j + 3];
        unsigned u0 = *(const unsigned*)(hb + (size_t)s0 * HH + ci * 2);
        unsigned u1 = *(const unsigned*)(hb + (size_t)s1 * HH + ci * 2);
        unsigned u2 = *(const unsigned*)(hb + (size_t)s2 * HH + ci * 2);
        unsigned u3 = *(const unsigned*)(hb + (size_t)s3 * HH + ci * 2);
        a0 += frombf((unsigned short)u0); b0 += frombf((unsigned short)(u0 >> 16));
        a1 += frombf((unsigned short)u1); b1 += frombf((unsigned short)(u1 >> 16));
        a2 += frombf((unsigned short)u2); b2 += frombf((unsigned short)(u2 >> 16));
        a3 += frombf((unsigned short)u3); b3 += frombf((unsigned short)(u3 >> 16));
    }
    for (; j < en; ++j) {
        unsigned u = *(const unsigned*)(hb + (size_t)srt[j] * HH + ci * 2);
        a0 += frombf((unsigned short)u); b0 += frombf((unsigned short)(u >> 16));
    }
    float A = (a0 + a1) + (a2 + a3);
    float B = (b0 + b1) + (b2 + b3);
    unsigned o = (unsigned)tobf(A) | ((unsigned)tobf(B) << 16);
    *(unsigned*)(Sb + (size_t)n * HH + ci * 2) = o;
}

// convert 8 consecutive fp32 -> bf16x8 fragment
__device__ __forceinline__ s8v cvt8(const float* __restrict__ p) {
    s8v r;
#pragma unroll
    for (int i = 0; i < 8; ++i) r[i] = (short)tobf(p[i]);
    return r;
}

// MFMA GRU: h(inplace fp32) = GRU(Sb, h); also writes bf16 shadow hb.
__global__ __launch_bounds__(256, 3) void k_gru(const unsigned short* __restrict__ Sb,
                                                float* __restrict__ h,
                                                unsigned short* __restrict__ hb,
                                                const unsigned short* __restrict__ Wcp_t,
                                                const unsigned short* __restrict__ Whp,
                                                const float* __restrict__ b_ih,
                                                const float* __restrict__ b_hh) {
    __shared__ unsigned short wiL[12288];   // 24 KB
    __shared__ unsigned short whL[12288];   // 24 KB
    for (int i = threadIdx.x; i < 12288 / 8; i += 256) {
        ((ulonglong2*)wiL)[i] = ((const ulonglong2*)Wcp_t)[i];
        ((ulonglong2*)whL)[i] = ((const ulonglong2*)Whp)[i];
    }
    __syncthreads();
    const s8v* wiB = (const s8v*)wiL;
    const s8v* whB = (const s8v*)whL;

    int lane = threadIdx.x & 63;
    int wave = threadIdx.x >> 6;
    int quad = lane >> 4, nidx = lane & 15;
    int fwid = blockIdx.x * 4 + wave;
    int tot = gridDim.x * 4;

    float brz[4], bzz[4], bin[4], bhn[4];
#pragma unroll
    for (int t = 0; t < 4; ++t) {
        int c = t * 16 + nidx;
        brz[t] = b_ih[c] + b_hh[c];
        bzz[t] = b_ih[64 + c] + b_hh[64 + c];
        bin[t] = b_ih[128 + c];
        bhn[t] = b_hh[128 + c];
    }

    for (int g = fwid; g < NGRP; g += tot) {
        int n0 = g * 16;
        size_t rowoff = (size_t)(n0 + nidx) * HH + quad * 8;
        s8v aS0 = *(const s8v*)(Sb + rowoff);
        s8v aS1 = *(const s8v*)(Sb + rowoff + 32);
        s8v aH0 = cvt8(h + rowoff);
        s8v aH1 = cvt8(h + rowoff + 32);

        f4v accRZ[8], accIN[4], accHN[4];
#pragma unroll
        for (int t = 0; t < 4; ++t) {
            accRZ[t]     = (f4v){brz[t], brz[t], brz[t], brz[t]};
            accRZ[4 + t] = (f4v){bzz[t], bzz[t], bzz[t], bzz[t]};
            accIN[t]     = (f4v){bin[t], bin[t], bin[t], bin[t]};
            accHN[t]     = (f4v){bhn[t], bhn[t], bhn[t], bhn[t]};
        }
#pragma unroll
        for (int t = 0; t < 4; ++t) {
            accRZ[t] = __builtin_amdgcn_mfma_f32_16x16x32_bf16(aS0, wiB[(t * 2 + 0) * 64 + lane], accRZ[t], 0, 0, 0);
            accRZ[t] = __builtin_amdgcn_mfma_f32_16x16x32_bf16(aS1, wiB[(t * 2 + 1) * 64 + lane], accRZ[t], 0, 0, 0);
            accRZ[t] = __builtin_amdgcn_mfma_f32_16x16x32_bf16(aH0, whB[(t * 2 + 0) * 64 + lane], accRZ[t], 0, 0, 0);
            accRZ[t] = __builtin_amdgcn_mfma_f32_16x16x32_bf16(aH1, whB[(t * 2 + 1) * 64 + lane], accRZ[t], 0, 0, 0);
            int tz = t + 4;
            accRZ[4 + t] = __builtin_amdgcn_mfma_f32_16x16x32_bf16(aS0, wiB[(tz * 2 + 0) * 64 + lane], accRZ[4 + t], 0, 0, 0);
            accRZ[4 + t] = __builtin_amdgcn_mfma_f32_16x16x32_bf16(aS1, wiB[(tz * 2 + 1) * 64 + lane], accRZ[4 + t], 0, 0, 0);
            accRZ[4 + t] = __builtin_amdgcn_mfma_f32_16x16x32_bf16(aH0, whB[(tz * 2 + 0) * 64 + lane], accRZ[4 + t], 0, 0, 0);
            accRZ[4 + t] = __builtin_amdgcn_mfma_f32_16x16x32_bf16(aH1, whB[(tz * 2 + 1) * 64 + lane], accRZ[4 + t], 0, 0, 0);
            int tn = t + 8;
            accIN[t] = __builtin_amdgcn_mfma_f32_16x16x32_bf16(aS0, wiB[(tn * 2 + 0) * 64 + lane], accIN[t], 0, 0, 0);
            accIN[t] = __builtin_amdgcn_mfma_f32_16x16x32_bf16(aS1, wiB[(tn * 2 + 1) * 64 + lane], accIN[t], 0, 0, 0);
            accHN[t] = __builtin_amdgcn_mfma_f32_16x16x32_bf16(aH0, whB[(tn * 2 + 0) * 64 + lane], accHN[t], 0, 0, 0);
            accHN[t] = __builtin_amdgcn_mfma_f32_16x16x32_bf16(aH1, whB[(tn * 2 + 1) * 64 + lane], accHN[t], 0, 0, 0);
        }
#pragma unroll
        for (int t = 0; t < 4; ++t) {
            int c = t * 16 + nidx;
#pragma unroll
            for (int reg = 0; reg < 4; ++reg) {
                int node = n0 + quad * 4 + reg;
                float rv = sigf(accRZ[t][reg]);
                float zv = sigf(accRZ[4 + t][reg]);
                float nv = tanhfast(fmaf(rv, accHN[t][reg], accIN[t][reg]));
                size_t off = (size_t)node * HH + c;
                float ho = h[off];
                float hnew = fmaf(zv, ho - nv, nv);   // (1-z)n + z h
                h[off] = hnew;
                hb[off] = tobf(hnew);
            }
        }
    }
}

// out[i] = sigmoid(dot(h[idx[i]], W_lin) + b_lin)
__global__ __launch_bounds__(256) void k_readout(const float* __restrict__ h,
                                                 const int* __restrict__ idx,
                                                 const float* __restrict__ Wl,
                                                 const float* __restrict__ bl,
                                                 float* __restrict__ out, int B) {
    int gid = blockIdx.x * 256 + threadIdx.x;
    int i = gid >> 6, lane = gid & 63;
    if (i >= B) return;
    int n = idx[i];
    float v = h[(size_t)n * HH + lane] * Wl[lane];
#pragma unroll
    for (int off = 32; off > 0; off >>= 1) v += __shfl_xor(v, off, 64);
    if (lane == 0) out[i] = sigf(v + bl[0]);
}

extern "C" void kernel_launch(void* const* d_in, const int* in_sizes, int n_in,
                              void* d_out, int out_size, void* d_ws, size_t ws_size,
                              hipStream_t stream) {
    const float* x     = (const float*)d_in[0];
    const int*   ei    = (const int*)d_in[1];
    const int*   idx   = (const int*)d_in[2];
    const float* W_red = (const float*)d_in[3];
    const float* b_red = (const float*)d_in[4];
    const float* W_g   = (const float*)d_in[5];
    const float* w_ih  = (const float*)d_in[6];
    const float* w_hh  = (const float*)d_in[7];
    const float* b_ih  = (const float*)d_in[8];
    const float* b_hh  = (const float*)d_in[9];
    const float* W_lin = (const float*)d_in[10];
    const float* b_lin = (const float*)d_in[11];
    float* out = (float*)d_out;
    const int E = in_sizes[1] / 2;
    const int B = in_sizes[2];
    const int* src = ei;
    const int* dst = ei + E;

    float*          h   = (float*)d_ws;                          // [NN,64] fp32
    unsigned short* hb  = (unsigned short*)(h + (size_t)NN * HH);
    unsigned short* Sb  = hb + (size_t)NN * HH;
    unsigned short* Wcp = Sb + (size_t)NN * HH;
    unsigned short* Whp = Wcp + (size_t)NSTEP * 12288;
    int*            cur = (int*)(Whp + 12288);
    int*            srt = cur + NN;
    int*            bsum = srt + E;                               // [NB]

    // ---- CSR build (counting sort by dst, parallel scan) ----
    hipMemsetAsync(cur, 0, NN * sizeof(int), stream);
    k_hist<<<(E + 255) / 256, 256, 0, stream>>>(dst, cur, E);
    k_scan1<<<NB, 256, 0, stream>>>(cur, bsum);
    k_scan2<<<1, 512, 0, stream>>>(bsum);
    k_scan3<<<NB, 256, 0, stream>>>(cur, bsum);
    k_place<<<(E + 255) / 256, 256, 0, stream>>>(src, dst, cur, srt, E);

    // ---- node init + packed weights ----
    k_reduce<<<NN / 16, 256, 0, stream>>>(x, W_red, b_red, h, hb);
    k_wc<<<(NSTEP * 64 * 192 + 255) / 256, 256, 0, stream>>>(W_g, w_ih, Wcp);
    k_whp<<<(192 * 64 + 255) / 256, 256, 0, stream>>>(w_hh, Whp);

    // ---- 8 propagation steps ----
    for (int t = 0; t < NSTEP; ++t) {
        k_aggr<<<(NN / 2 * 64 + 255) / 256, 256, 0, stream>>>(hb, cur, srt, Sb);
        k_gru<<<782, 256, 0, stream>>>(Sb, h, hb, Wcp + (size_t)t * 12288, Whp,
                                       b_ih, b_hh);
    }

    k_readout<<<(B * 64 + 255) / 256, 256, 0, stream>>>(h, idx, W_lin, b_lin, out, B);
}

// Round 7
// 1212.329 us; speedup vs baseline: 1.9089x; 1.0721x over previous
//
#include <hip/hip_runtime.h>
#include <hip/hip_bf16.h>

#define NN 100000
#define HH 64
#define AN 92
#define NSTEP 8
#define NGRP 6250          // NN / 16, exact
#define NB 391             // ceil(NN / 256)

typedef float f4v __attribute__((ext_vector_type(4)));
typedef short s8v __attribute__((ext_vector_type(8)));

__device__ __forceinline__ float sigf(float x) { return 1.0f / (1.0f + __expf(-x)); }
// tanh(x) = 1 - 2/(1+e^{2x}); saturates correctly, no NaN.
__device__ __forceinline__ float tanhfast(float x) { return 1.0f - 2.0f / (1.0f + __expf(2.0f * x)); }

__device__ __forceinline__ unsigned short tobf(float x) {
    __hip_bfloat16 b = __float2bfloat16(x);   // RNE
    return __builtin_bit_cast(unsigned short, b);
}
__device__ __forceinline__ float frombf(unsigned short u) {
    return __int_as_float(((unsigned)u) << 16);
}

// h = x @ W_red + b. 16 nodes/block; x rows staged to LDS coalesced;
// compute via LDS broadcasts. Writes fp32 h and bf16 shadow hb.
__global__ __launch_bounds__(256) void k_reduce(const float* __restrict__ x,
                                                const float* __restrict__ W,
                                                const float* __restrict__ b,
                                                float* __restrict__ h,
                                                unsigned short* __restrict__ hb) {
    __shared__ float xl[16][96];      // k padded to 96, pads zeroed
    __shared__ float wl[96 * 64];     // wl[k*64+j] = W[k][j]; k=92..95 zeroed
    int tid = threadIdx.x;
    int n0 = blockIdx.x * 16;         // NN % 16 == 0 -> no tail
    for (int i = tid; i < 16 * AN; i += 256)
        xl[i / AN][i % AN] = x[(size_t)n0 * AN + i];
    if (tid < 64) xl[tid >> 2][AN + (tid & 3)] = 0.f;
    for (int i = tid; i < AN * 64; i += 256) wl[i] = W[i];
    wl[AN * 64 + tid] = 0.f;
    __syncthreads();
    int lane = tid & 63, wave = tid >> 6;
    float a[4];
    float bj = b[lane];
#pragma unroll
    for (int u = 0; u < 4; ++u) a[u] = bj;
#pragma unroll
    for (int k4 = 0; k4 < 96; k4 += 4) {
        float4 xv[4];
#pragma unroll
        for (int u = 0; u < 4; ++u) xv[u] = *(const float4*)&xl[wave * 4 + u][k4];
#pragma unroll
        for (int kk = 0; kk < 4; ++kk) {
            float wv = wl[(k4 + kk) * 64 + lane];
            a[0] = fmaf(((const float*)&xv[0])[kk], wv, a[0]);
            a[1] = fmaf(((const float*)&xv[1])[kk], wv, a[1]);
            a[2] = fmaf(((const float*)&xv[2])[kk], wv, a[2]);
            a[3] = fmaf(((const float*)&xv[3])[kk], wv, a[3]);
        }
    }
#pragma unroll
    for (int u = 0; u < 4; ++u) {
        int n = n0 + wave * 4 + u;
        h[(size_t)n * HH + lane] = a[u];
        hb[(size_t)n * HH + lane] = tobf(a[u]);
    }
}

// Packed B-fragment position for mfma_f32_16x16x32_bf16:
// element B[k][r] lives at ((T*2+kh)*64 + lane)*8 + j,
// T=r>>4, kh=k>>5, lane=((k>>3)&3)*16 + (r&15), j=k&7.
__device__ __forceinline__ int packpos(int k, int r) {
    int T = r >> 4, kh = k >> 5;
    int lane = ((k >> 3) & 3) * 16 + (r & 15);
    int j = k & 7;
    return ((T * 2 + kh) * 64 + lane) * 8 + j;
}

// Wc[t][k][r] = sum_q W_g[t][k][q] * w_ih[r][q], bf16 in packed B-frag order.
__global__ __launch_bounds__(256) void k_wc(const float* __restrict__ Wg,
                                            const float* __restrict__ w_ih,
                                            unsigned short* __restrict__ Wcp) {
    __shared__ float wl[192 * 65];
    for (int i = threadIdx.x; i < 192 * 64; i += 256) {
        int r = i >> 6, q = i & 63;
        wl[r * 65 + q] = w_ih[i];
    }
    __syncthreads();
    int gid = blockIdx.x * 256 + threadIdx.x;
    if (gid >= NSTEP * 64 * 192) return;
    int r = gid % 192;
    int k = (gid / 192) & 63;
    int t = gid / (192 * 64);
    const float* wg = Wg + t * 4096 + k * 64;
    float acc = 0.f;
#pragma unroll
    for (int q = 0; q < 64; ++q) acc = fmaf(wg[q], wl[r * 65 + q], acc);
    Wcp[t * 12288 + packpos(k, r)] = tobf(acc);
}

// Whp packed: B[k][r] = w_hh[r][k]  (for gh = h @ w_hh^T)
__global__ __launch_bounds__(256) void k_whp(const float* __restrict__ w_hh,
                                             unsigned short* __restrict__ Whp) {
    int gid = blockIdx.x * 256 + threadIdx.x;
    if (gid >= 192 * 64) return;
    int r = gid >> 6, k = gid & 63;
    Whp[packpos(k, r)] = tobf(w_hh[r * 64 + k]);
}

// cur[dst[e]]++
__global__ __launch_bounds__(256) void k_hist(const int* __restrict__ dst, int* __restrict__ cur, int E) {
    int e = blockIdx.x * 256 + threadIdx.x;
    if (e >= E) return;
    atomicAdd(cur + dst[e], 1);
}

// ---- parallel 3-phase exclusive scan of cur[0..NN) ----
__global__ __launch_bounds__(256) void k_scan1(const int* __restrict__ cur, int* __restrict__ bsum) {
    __shared__ int ws[4];
    int gid = blockIdx.x * 256 + threadIdx.x;
    int lane = threadIdx.x & 63, wave = threadIdx.x >> 6;
    int v = (gid < NN) ? cur[gid] : 0;
#pragma unroll
    for (int off = 32; off > 0; off >>= 1) v += __shfl_xor(v, off, 64);
    if (lane == 0) ws[wave] = v;
    __syncthreads();
    if (threadIdx.x == 0) bsum[blockIdx.x] = ws[0] + ws[1] + ws[2] + ws[3];
}

__global__ __launch_bounds__(512) void k_scan2(int* __restrict__ bsum) {
    __shared__ int s[512];
    int t = threadIdx.x;
    int v = (t < NB) ? bsum[t] : 0;
    s[t] = v;
    __syncthreads();
    for (int off = 1; off < 512; off <<= 1) {
        int w = (t >= off) ? s[t - off] : 0;
        __syncthreads();
        s[t] += w;
        __syncthreads();
    }
    if (t < NB) bsum[t] = s[t] - v;   // exclusive
}

__global__ __launch_bounds__(256) void k_scan3(int* __restrict__ cur, const int* __restrict__ bsum) {
    __shared__ int ws[4];
    int gid = blockIdx.x * 256 + threadIdx.x;
    int lane = threadIdx.x & 63, wave = threadIdx.x >> 6;
    int orig = (gid < NN) ? cur[gid] : 0;
    int v = orig;
#pragma unroll
    for (int off = 1; off < 64; off <<= 1) {
        int w = __shfl_up(v, off, 64);
        if (lane >= off) v += w;
    }
    if (lane == 63) ws[wave] = v;
    __syncthreads();
    int woff = 0;
    for (int w = 0; w < 4; ++w) woff += (w < wave) ? ws[w] : 0;
    if (gid < NN) cur[gid] = v - orig + woff + bsum[blockIdx.x];
}

// srt[cur[dst[e]]++] = src[e]   (after: cur[n] = end offset of segment n)
__global__ __launch_bounds__(256) void k_place(const int* __restrict__ src,
                                               const int* __restrict__ dst,
                                               int* __restrict__ cur,
                                               int* __restrict__ srt, int E) {
    int e = blockIdx.x * 256 + threadIdx.x;
    if (e >= E) return;
    int pos = atomicAdd(cur + dst[e], 1);
    srt[pos] = src[e];
}

// Sb[n][:] = bf16( sum over in-edges of hb[src][:] ).
// 2 nodes per wave (half-wave = full 128B row); 4-deep edge unroll.
__global__ __launch_bounds__(256) void k_aggr(const unsigned short* __restrict__ hb,
                                              const int* __restrict__ cur,
                                              const int* __restrict__ srt,
                                              unsigned short* __restrict__ Sb) {
    int gid = blockIdx.x * 256 + threadIdx.x;
    int wid = gid >> 6;
    int lane = threadIdx.x & 63;
    int half = lane >> 5;
    int ci = lane & 31;
    int n = wid * 2 + half;
    if (n >= NN) return;
    int st = (n == 0) ? 0 : cur[n - 1];
    int en = cur[n];
    float a0 = 0.f, b0 = 0.f, a1 = 0.f, b1 = 0.f;
    float a2 = 0.f, b2 = 0.f, a3 = 0.f, b3 = 0.f;
    int j = st;
    for (; j + 4 <= en; j += 4) {
        int s0 = srt[j], s1 = srt[j + 1], s2 = srt[j + 2], s3 = srt[j + 3];
        unsigned u0 = *(const unsigned*)(hb + (size_t)s0 * HH + ci * 2);
        unsigned u1 = *(const unsigned*)(hb + (size_t)s1 * HH + ci * 2);
        unsigned u2 = *(const unsigned*)(hb + (size_t)s2 * HH + ci * 2);
        unsigned u3 = *(const unsigned*)(hb + (size_t)s3 * HH + ci * 2);
        a0 += frombf((unsigned short)u0); b0 += frombf((unsigned short)(u0 >> 16));
        a1 += frombf((unsigned short)u1); b1 += frombf((unsigned short)(u1 >> 16));
        a2 += frombf((unsigned short)u2); b2 += frombf((unsigned short)(u2 >> 16));
        a3 += frombf((unsigned short)u3); b3 += frombf((unsigned short)(u3 >> 16));
    }
    for (; j < en; ++j) {
        unsigned u = *(const unsigned*)(hb + (size_t)srt[j] * HH + ci * 2);
        a0 += frombf((unsigned short)u); b0 += frombf((unsigned short)(u >> 16));
    }
    float A = (a0 + a1) + (a2 + a3);
    float B = (b0 + b1) + (b2 + b3);
    unsigned o = (unsigned)tobf(A) | ((unsigned)tobf(B) << 16);
    *(unsigned*)(Sb + (size_t)n * HH + ci * 2) = o;
}

// convert 8 consecutive fp32 -> bf16x8 fragment
__device__ __forceinline__ s8v cvt8(const float* __restrict__ p) {
    s8v r;
#pragma unroll
    for (int i = 0; i < 8; ++i) r[i] = (short)tobf(p[i]);
    return r;
}

// MFMA GRU: h(inplace fp32) = GRU(Sb, h); also writes bf16 shadow hb.
// Epilogue fused into the t-loop: only 4 acc tiles (16 VGPRs) live at a
// time -> no spills (Round-6's 170/173 MB symmetric scratch traffic).
__global__ __launch_bounds__(256, 3) void k_gru(const unsigned short* __restrict__ Sb,
                                                float* __restrict__ h,
                                                unsigned short* __restrict__ hb,
                                                const unsigned short* __restrict__ Wcp_t,
                                                const unsigned short* __restrict__ Whp,
                                                const float* __restrict__ b_ih,
                                                const float* __restrict__ b_hh) {
    __shared__ unsigned short wiL[12288];   // 24 KB
    __shared__ unsigned short whL[12288];   // 24 KB
    for (int i = threadIdx.x; i < 12288 / 8; i += 256) {
        ((ulonglong2*)wiL)[i] = ((const ulonglong2*)Wcp_t)[i];
        ((ulonglong2*)whL)[i] = ((const ulonglong2*)Whp)[i];
    }
    __syncthreads();
    const s8v* wiB = (const s8v*)wiL;
    const s8v* whB = (const s8v*)whL;

    int lane = threadIdx.x & 63;
    int wave = threadIdx.x >> 6;
    int quad = lane >> 4, nidx = lane & 15;
    int fwid = blockIdx.x * 4 + wave;
    int tot = gridDim.x * 4;

    float brz[4], bzz[4], bin[4], bhn[4];
#pragma unroll
    for (int t = 0; t < 4; ++t) {
        int c = t * 16 + nidx;
        brz[t] = b_ih[c] + b_hh[c];
        bzz[t] = b_ih[64 + c] + b_hh[64 + c];
        bin[t] = b_ih[128 + c];
        bhn[t] = b_hh[128 + c];
    }

    for (int g = fwid; g < NGRP; g += tot) {
        int n0 = g * 16;
        size_t rowoff = (size_t)(n0 + nidx) * HH + quad * 8;
        s8v aS0 = *(const s8v*)(Sb + rowoff);
        s8v aS1 = *(const s8v*)(Sb + rowoff + 32);
        s8v aH0 = cvt8(h + rowoff);
        s8v aH1 = cvt8(h + rowoff + 32);

#pragma unroll
        for (int t = 0; t < 4; ++t) {
            f4v aRZ0 = {brz[t], brz[t], brz[t], brz[t]};
            f4v aRZ1 = {bzz[t], bzz[t], bzz[t], bzz[t]};
            f4v aIN  = {bin[t], bin[t], bin[t], bin[t]};
            f4v aHN  = {bhn[t], bhn[t], bhn[t], bhn[t]};
            // r gate (cols t*16..): tile index t
            aRZ0 = __builtin_amdgcn_mfma_f32_16x16x32_bf16(aS0, wiB[(t * 2 + 0) * 64 + lane], aRZ0, 0, 0, 0);
            aRZ0 = __builtin_amdgcn_mfma_f32_16x16x32_bf16(aS1, wiB[(t * 2 + 1) * 64 + lane], aRZ0, 0, 0, 0);
            aRZ0 = __builtin_amdgcn_mfma_f32_16x16x32_bf16(aH0, whB[(t * 2 + 0) * 64 + lane], aRZ0, 0, 0, 0);
            aRZ0 = __builtin_amdgcn_mfma_f32_16x16x32_bf16(aH1, whB[(t * 2 + 1) * 64 + lane], aRZ0, 0, 0, 0);
            // z gate: tile t+4
            int tz = t + 4;
            aRZ1 = __builtin_amdgcn_mfma_f32_16x16x32_bf16(aS0, wiB[(tz * 2 + 0) * 64 + lane], aRZ1, 0, 0, 0);
            aRZ1 = __builtin_amdgcn_mfma_f32_16x16x32_bf16(aS1, wiB[(tz * 2 + 1) * 64 + lane], aRZ1, 0, 0, 0);
            aRZ1 = __builtin_amdgcn_mfma_f32_16x16x32_bf16(aH0, whB[(tz * 2 + 0) * 64 + lane], aRZ1, 0, 0, 0);
            aRZ1 = __builtin_amdgcn_mfma_f32_16x16x32_bf16(aH1, whB[(tz * 2 + 1) * 64 + lane], aRZ1, 0, 0, 0);
            // n gate: tile t+8, gi and gh SEPARATE
            int tn = t + 8;
            aIN = __builtin_amdgcn_mfma_f32_16x16x32_bf16(aS0, wiB[(tn * 2 + 0) * 64 + lane], aIN, 0, 0, 0);
            aIN = __builtin_amdgcn_mfma_f32_16x16x32_bf16(aS1, wiB[(tn * 2 + 1) * 64 + lane], aIN, 0, 0, 0);
            aHN = __builtin_amdgcn_mfma_f32_16x16x32_bf16(aH0, whB[(tn * 2 + 0) * 64 + lane], aHN, 0, 0, 0);
            aHN = __builtin_amdgcn_mfma_f32_16x16x32_bf16(aH1, whB[(tn * 2 + 1) * 64 + lane], aHN, 0, 0, 0);
            // fused epilogue for this tile: cols c = t*16+nidx, rows quad*4+reg
            int c = t * 16 + nidx;
#pragma unroll
            for (int reg = 0; reg < 4; ++reg) {
                int node = n0 + quad * 4 + reg;
                float rv = sigf(aRZ0[reg]);
                float zv = sigf(aRZ1[reg]);
                float nv = tanhfast(fmaf(rv, aHN[reg], aIN[reg]));
                size_t off = (size_t)node * HH + c;
                float ho = h[off];
                float hnew = fmaf(zv, ho - nv, nv);   // (1-z)n + z h
                h[off] = hnew;
                hb[off] = tobf(hnew);
            }
        }
    }
}

// out[i] = sigmoid(dot(h[idx[i]], W_lin) + b_lin)
__global__ __launch_bounds__(256) void k_readout(const float* __restrict__ h,
                                                 const int* __restrict__ idx,
                                                 const float* __restrict__ Wl,
                                                 const float* __restrict__ bl,
                                                 float* __restrict__ out, int B) {
    int gid = blockIdx.x * 256 + threadIdx.x;
    int i = gid >> 6, lane = gid & 63;
    if (i >= B) return;
    int n = idx[i];
    float v = h[(size_t)n * HH + lane] * Wl[lane];
#pragma unroll
    for (int off = 32; off > 0; off >>= 1) v += __shfl_xor(v, off, 64);
    if (lane == 0) out[i] = sigf(v + bl[0]);
}

extern "C" void kernel_launch(void* const* d_in, const int* in_sizes, int n_in,
                              void* d_out, int out_size, void* d_ws, size_t ws_size,
                              hipStream_t stream) {
    const float* x     = (const float*)d_in[0];
    const int*   ei    = (const int*)d_in[1];
    const int*   idx   = (const int*)d_in[2];
    const float* W_red = (const float*)d_in[3];
    const float* b_red = (const float*)d_in[4];
    const float* W_g   = (const float*)d_in[5];
    const float* w_ih  = (const float*)d_in[6];
    const float* w_hh  = (const float*)d_in[7];
    const float* b_ih  = (const float*)d_in[8];
    const float* b_hh  = (const float*)d_in[9];
    const float* W_lin = (const float*)d_in[10];
    const float* b_lin = (const float*)d_in[11];
    float* out = (float*)d_out;
    const int E = in_sizes[1] / 2;
    const int B = in_sizes[2];
    const int* src = ei;
    const int* dst = ei + E;

    float*          h   = (float*)d_ws;                          // [NN,64] fp32
    unsigned short* hb  = (unsigned short*)(h + (size_t)NN * HH);
    unsigned short* Sb  = hb + (size_t)NN * HH;
    unsigned short* Wcp = Sb + (size_t)NN * HH;
    unsigned short* Whp = Wcp + (size_t)NSTEP * 12288;
    int*            cur = (int*)(Whp + 12288);
    int*            srt = cur + NN;
    int*            bsum = srt + E;                               // [NB]

    // ---- CSR build (counting sort by dst, parallel scan) ----
    hipMemsetAsync(cur, 0, NN * sizeof(int), stream);
    k_hist<<<(E + 255) / 256, 256, 0, stream>>>(dst, cur, E);
    k_scan1<<<NB, 256, 0, stream>>>(cur, bsum);
    k_scan2<<<1, 512, 0, stream>>>(bsum);
    k_scan3<<<NB, 256, 0, stream>>>(cur, bsum);
    k_place<<<(E + 255) / 256, 256, 0, stream>>>(src, dst, cur, srt, E);

    // ---- node init + packed weights ----
    k_reduce<<<NN / 16, 256, 0, stream>>>(x, W_red, b_red, h, hb);
    k_wc<<<(NSTEP * 64 * 192 + 255) / 256, 256, 0, stream>>>(W_g, w_ih, Wcp);
    k_whp<<<(192 * 64 + 255) / 256, 256, 0, stream>>>(w_hh, Whp);

    // ---- 8 propagation steps ----
    for (int t = 0; t < NSTEP; ++t) {
        k_aggr<<<(NN / 2 * 64 + 255) / 256, 256, 0, stream>>>(hb, cur, srt, Sb);
        k_gru<<<782, 256, 0, stream>>>(Sb, h, hb, Wcp + (size_t)t * 12288, Whp,
                                       b_ih, b_hh);
    }

    k_readout<<<(B * 64 + 255) / 256, 256, 0, stream>>>(h, idx, W_lin, b_lin, out, B);
}

// Round 8
// 749.320 us; speedup vs baseline: 3.0884x; 1.6179x over previous
//
#include <hip/hip_runtime.h>
#include <hip/hip_bf16.h>

#define NN 100000
#define HH 64
#define AN 92
#define NSTEP 8
#define NGRP 6250          // NN / 16, exact
#define NB 391             // ceil(NN / 256)

typedef float f4v __attribute__((ext_vector_type(4)));
typedef short s8v __attribute__((ext_vector_type(8)));

__device__ __forceinline__ float sigf(float x) { return 1.0f / (1.0f + __expf(-x)); }
// tanh(x) = 1 - 2/(1+e^{2x}); saturates correctly, no NaN.
__device__ __forceinline__ float tanhfast(float x) { return 1.0f - 2.0f / (1.0f + __expf(2.0f * x)); }

__device__ __forceinline__ unsigned short tobf(float x) {
    __hip_bfloat16 b = __float2bfloat16(x);   // RNE
    return __builtin_bit_cast(unsigned short, b);
}
__device__ __forceinline__ float frombf(unsigned short u) {
    return __int_as_float(((unsigned)u) << 16);
}

// h = x @ W_red + b. 16 nodes/block; x rows staged to LDS coalesced;
// compute via LDS broadcasts. Writes fp32 h and bf16 shadow hb.
__global__ __launch_bounds__(256) void k_reduce(const float* __restrict__ x,
                                                const float* __restrict__ W,
                                                const float* __restrict__ b,
                                                float* __restrict__ h,
                                                unsigned short* __restrict__ hb) {
    __shared__ float xl[16][96];      // k padded to 96, pads zeroed
    __shared__ float wl[96 * 64];     // wl[k*64+j] = W[k][j]; k=92..95 zeroed
    int tid = threadIdx.x;
    int n0 = blockIdx.x * 16;         // NN % 16 == 0 -> no tail
    for (int i = tid; i < 16 * AN; i += 256)
        xl[i / AN][i % AN] = x[(size_t)n0 * AN + i];
    if (tid < 64) xl[tid >> 2][AN + (tid & 3)] = 0.f;
    for (int i = tid; i < AN * 64; i += 256) wl[i] = W[i];
    wl[AN * 64 + tid] = 0.f;
    __syncthreads();
    int lane = tid & 63, wave = tid >> 6;
    float a[4];
    float bj = b[lane];
#pragma unroll
    for (int u = 0; u < 4; ++u) a[u] = bj;
#pragma unroll
    for (int k4 = 0; k4 < 96; k4 += 4) {
        float4 xv[4];
#pragma unroll
        for (int u = 0; u < 4; ++u) xv[u] = *(const float4*)&xl[wave * 4 + u][k4];
#pragma unroll
        for (int kk = 0; kk < 4; ++kk) {
            float wv = wl[(k4 + kk) * 64 + lane];
            a[0] = fmaf(((const float*)&xv[0])[kk], wv, a[0]);
            a[1] = fmaf(((const float*)&xv[1])[kk], wv, a[1]);
            a[2] = fmaf(((const float*)&xv[2])[kk], wv, a[2]);
            a[3] = fmaf(((const float*)&xv[3])[kk], wv, a[3]);
        }
    }
#pragma unroll
    for (int u = 0; u < 4; ++u) {
        int n = n0 + wave * 4 + u;
        h[(size_t)n * HH + lane] = a[u];
        hb[(size_t)n * HH + lane] = tobf(a[u]);
    }
}

// Packed B-fragment position for mfma_f32_16x16x32_bf16:
// element B[k][r] lives at ((T*2+kh)*64 + lane)*8 + j,
// T=r>>4, kh=k>>5, lane=((k>>3)&3)*16 + (r&15), j=k&7.
__device__ __forceinline__ int packpos(int k, int r) {
    int T = r >> 4, kh = k >> 5;
    int lane = ((k >> 3) & 3) * 16 + (r & 15);
    int j = k & 7;
    return ((T * 2 + kh) * 64 + lane) * 8 + j;
}

// Wc[t][k][r] = sum_q W_g[t][k][q] * w_ih[r][q], bf16 in packed B-frag order.
__global__ __launch_bounds__(256) void k_wc(const float* __restrict__ Wg,
                                            const float* __restrict__ w_ih,
                                            unsigned short* __restrict__ Wcp) {
    __shared__ float wl[192 * 65];
    for (int i = threadIdx.x; i < 192 * 64; i += 256) {
        int r = i >> 6, q = i & 63;
        wl[r * 65 + q] = w_ih[i];
    }
    __syncthreads();
    int gid = blockIdx.x * 256 + threadIdx.x;
    if (gid >= NSTEP * 64 * 192) return;
    int r = gid % 192;
    int k = (gid / 192) & 63;
    int t = gid / (192 * 64);
    const float* wg = Wg + t * 4096 + k * 64;
    float acc = 0.f;
#pragma unroll
    for (int q = 0; q < 64; ++q) acc = fmaf(wg[q], wl[r * 65 + q], acc);
    Wcp[t * 12288 + packpos(k, r)] = tobf(acc);
}

// Whp packed: B[k][r] = w_hh[r][k]  (for gh = h @ w_hh^T)
__global__ __launch_bounds__(256) void k_whp(const float* __restrict__ w_hh,
                                             unsigned short* __restrict__ Whp) {
    int gid = blockIdx.x * 256 + threadIdx.x;
    if (gid >= 192 * 64) return;
    int r = gid >> 6, k = gid & 63;
    Whp[packpos(k, r)] = tobf(w_hh[r * 64 + k]);
}

// cur[dst[e]]++
__global__ __launch_bounds__(256) void k_hist(const int* __restrict__ dst, int* __restrict__ cur, int E) {
    int e = blockIdx.x * 256 + threadIdx.x;
    if (e >= E) return;
    atomicAdd(cur + dst[e], 1);
}

// ---- parallel 3-phase exclusive scan of cur[0..NN) ----
__global__ __launch_bounds__(256) void k_scan1(const int* __restrict__ cur, int* __restrict__ bsum) {
    __shared__ int ws[4];
    int gid = blockIdx.x * 256 + threadIdx.x;
    int lane = threadIdx.x & 63, wave = threadIdx.x >> 6;
    int v = (gid < NN) ? cur[gid] : 0;
#pragma unroll
    for (int off = 32; off > 0; off >>= 1) v += __shfl_xor(v, off, 64);
    if (lane == 0) ws[wave] = v;
    __syncthreads();
    if (threadIdx.x == 0) bsum[blockIdx.x] = ws[0] + ws[1] + ws[2] + ws[3];
}

__global__ __launch_bounds__(512) void k_scan2(int* __restrict__ bsum) {
    __shared__ int s[512];
    int t = threadIdx.x;
    int v = (t < NB) ? bsum[t] : 0;
    s[t] = v;
    __syncthreads();
    for (int off = 1; off < 512; off <<= 1) {
        int w = (t >= off) ? s[t - off] : 0;
        __syncthreads();
        s[t] += w;
        __syncthreads();
    }
    if (t < NB) bsum[t] = s[t] - v;   // exclusive
}

__global__ __launch_bounds__(256) void k_scan3(int* __restrict__ cur, const int* __restrict__ bsum) {
    __shared__ int ws[4];
    int gid = blockIdx.x * 256 + threadIdx.x;
    int lane = threadIdx.x & 63, wave = threadIdx.x >> 6;
    int orig = (gid < NN) ? cur[gid] : 0;
    int v = orig;
#pragma unroll
    for (int off = 1; off < 64; off <<= 1) {
        int w = __shfl_up(v, off, 64);
        if (lane >= off) v += w;
    }
    if (lane == 63) ws[wave] = v;
    __syncthreads();
    int woff = 0;
    for (int w = 0; w < 4; ++w) woff += (w < wave) ? ws[w] : 0;
    if (gid < NN) cur[gid] = v - orig + woff + bsum[blockIdx.x];
}

// srt[cur[dst[e]]++] = src[e]   (after: cur[n] = end offset of segment n)
__global__ __launch_bounds__(256) void k_place(const int* __restrict__ src,
                                               const int* __restrict__ dst,
                                               int* __restrict__ cur,
                                               int* __restrict__ srt, int E) {
    int e = blockIdx.x * 256 + threadIdx.x;
    if (e >= E) return;
    int pos = atomicAdd(cur + dst[e], 1);
    srt[pos] = src[e];
}

// Sb[n][:] = bf16( sum over in-edges of hb[src][:] ).
// 2 nodes per wave (half-wave = full 128B row); 4-deep edge unroll.
__global__ __launch_bounds__(256) void k_aggr(const unsigned short* __restrict__ hb,
                                              const int* __restrict__ cur,
                                              const int* __restrict__ srt,
                                              unsigned short* __restrict__ Sb) {
    int gid = blockIdx.x * 256 + threadIdx.x;
    int wid = gid >> 6;
    int lane = threadIdx.x & 63;
    int half = lane >> 5;
    int ci = lane & 31;
    int n = wid * 2 + half;
    if (n >= NN) return;
    int st = (n == 0) ? 0 : cur[n - 1];
    int en = cur[n];
    float a0 = 0.f, b0 = 0.f, a1 = 0.f, b1 = 0.f;
    float a2 = 0.f, b2 = 0.f, a3 = 0.f, b3 = 0.f;
    int j = st;
    for (; j + 4 <= en; j += 4) {
        int s0 = srt[j], s1 = srt[j + 1], s2 = srt[j + 2], s3 = srt[j + 3];
        unsigned u0 = *(const unsigned*)(hb + (size_t)s0 * HH + ci * 2);
        unsigned u1 = *(const unsigned*)(hb + (size_t)s1 * HH + ci * 2);
        unsigned u2 = *(const unsigned*)(hb + (size_t)s2 * HH + ci * 2);
        unsigned u3 = *(const unsigned*)(hb + (size_t)s3 * HH + ci * 2);
        a0 += frombf((unsigned short)u0); b0 += frombf((unsigned short)(u0 >> 16));
        a1 += frombf((unsigned short)u1); b1 += frombf((unsigned short)(u1 >> 16));
        a2 += frombf((unsigned short)u2); b2 += frombf((unsigned short)(u2 >> 16));
        a3 += frombf((unsigned short)u3); b3 += frombf((unsigned short)(u3 >> 16));
    }
    for (; j < en; ++j) {
        unsigned u = *(const unsigned*)(hb + (size_t)srt[j] * HH + ci * 2);
        a0 += frombf((unsigned short)u); b0 += frombf((unsigned short)(u >> 16));
    }
    float A = (a0 + a1) + (a2 + a3);
    float B = (b0 + b1) + (b2 + b3);
    unsigned o = (unsigned)tobf(A) | ((unsigned)tobf(B) << 16);
    *(unsigned*)(Sb + (size_t)n * HH + ci * 2) = o;
}

// convert 8 consecutive fp32 -> bf16x8 fragment
__device__ __forceinline__ s8v cvt8(const float* __restrict__ p) {
    s8v r;
#pragma unroll
    for (int i = 0; i < 8; ++i) r[i] = (short)tobf(p[i]);
    return r;
}

// MFMA GRU: h(inplace fp32) = GRU(Sb, h); also writes bf16 shadow hb.
// __launch_bounds__(256) ONLY: R6/R7's (256,3) min-occupancy hint capped the
// allocator at 84 VGPRs and spilled ~64 regs/group (the symmetric ~110 MB
// excess FETCH/WRITE). Full 256-reg budget -> no spill; LDS (48KB) already
// limits blocks/CU, so the occupancy hint bought nothing.
__global__ __launch_bounds__(256) void k_gru(const unsigned short* __restrict__ Sb,
                                             float* __restrict__ h,
                                             unsigned short* __restrict__ hb,
                                             const unsigned short* __restrict__ Wcp_t,
                                             const unsigned short* __restrict__ Whp,
                                             const float* __restrict__ b_ih,
                                             const float* __restrict__ b_hh) {
    __shared__ unsigned short wiL[12288];   // 24 KB
    __shared__ unsigned short whL[12288];   // 24 KB
    for (int i = threadIdx.x; i < 12288 / 8; i += 256) {
        ((ulonglong2*)wiL)[i] = ((const ulonglong2*)Wcp_t)[i];
        ((ulonglong2*)whL)[i] = ((const ulonglong2*)Whp)[i];
    }
    __syncthreads();
    const s8v* wiB = (const s8v*)wiL;
    const s8v* whB = (const s8v*)whL;

    int lane = threadIdx.x & 63;
    int wave = threadIdx.x >> 6;
    int quad = lane >> 4, nidx = lane & 15;
    int fwid = blockIdx.x * 4 + wave;
    int tot = gridDim.x * 4;

    float brz[4], bzz[4], bin[4], bhn[4];
#pragma unroll
    for (int t = 0; t < 4; ++t) {
        int c = t * 16 + nidx;
        brz[t] = b_ih[c] + b_hh[c];
        bzz[t] = b_ih[64 + c] + b_hh[64 + c];
        bin[t] = b_ih[128 + c];
        bhn[t] = b_hh[128 + c];
    }

    for (int g = fwid; g < NGRP; g += tot) {
        int n0 = g * 16;
        size_t rowoff = (size_t)(n0 + nidx) * HH + quad * 8;
        s8v aS0 = *(const s8v*)(Sb + rowoff);
        s8v aS1 = *(const s8v*)(Sb + rowoff + 32);
        s8v aH0 = cvt8(h + rowoff);
        s8v aH1 = cvt8(h + rowoff + 32);

#pragma unroll
        for (int t = 0; t < 4; ++t) {
            f4v aRZ0 = {brz[t], brz[t], brz[t], brz[t]};
            f4v aRZ1 = {bzz[t], bzz[t], bzz[t], bzz[t]};
            f4v aIN  = {bin[t], bin[t], bin[t], bin[t]};
            f4v aHN  = {bhn[t], bhn[t], bhn[t], bhn[t]};
            // r gate (cols t*16..): tile index t
            aRZ0 = __builtin_amdgcn_mfma_f32_16x16x32_bf16(aS0, wiB[(t * 2 + 0) * 64 + lane], aRZ0, 0, 0, 0);
            aRZ0 = __builtin_amdgcn_mfma_f32_16x16x32_bf16(aS1, wiB[(t * 2 + 1) * 64 + lane], aRZ0, 0, 0, 0);
            aRZ0 = __builtin_amdgcn_mfma_f32_16x16x32_bf16(aH0, whB[(t * 2 + 0) * 64 + lane], aRZ0, 0, 0, 0);
            aRZ0 = __builtin_amdgcn_mfma_f32_16x16x32_bf16(aH1, whB[(t * 2 + 1) * 64 + lane], aRZ0, 0, 0, 0);
            // z gate: tile t+4
            int tz = t + 4;
            aRZ1 = __builtin_amdgcn_mfma_f32_16x16x32_bf16(aS0, wiB[(tz * 2 + 0) * 64 + lane], aRZ1, 0, 0, 0);
            aRZ1 = __builtin_amdgcn_mfma_f32_16x16x32_bf16(aS1, wiB[(tz * 2 + 1) * 64 + lane], aRZ1, 0, 0, 0);
            aRZ1 = __builtin_amdgcn_mfma_f32_16x16x32_bf16(aH0, whB[(tz * 2 + 0) * 64 + lane], aRZ1, 0, 0, 0);
            aRZ1 = __builtin_amdgcn_mfma_f32_16x16x32_bf16(aH1, whB[(tz * 2 + 1) * 64 + lane], aRZ1, 0, 0, 0);
            // n gate: tile t+8, gi and gh SEPARATE
            int tn = t + 8;
            aIN = __builtin_amdgcn_mfma_f32_16x16x32_bf16(aS0, wiB[(tn * 2 + 0) * 64 + lane], aIN, 0, 0, 0);
            aIN = __builtin_amdgcn_mfma_f32_16x16x32_bf16(aS1, wiB[(tn * 2 + 1) * 64 + lane], aIN, 0, 0, 0);
            aHN = __builtin_amdgcn_mfma_f32_16x16x32_bf16(aH0, whB[(tn * 2 + 0) * 64 + lane], aHN, 0, 0, 0);
            aHN = __builtin_amdgcn_mfma_f32_16x16x32_bf16(aH1, whB[(tn * 2 + 1) * 64 + lane], aHN, 0, 0, 0);
            // fused epilogue for this tile: cols c = t*16+nidx, rows quad*4+reg
            int c = t * 16 + nidx;
#pragma unroll
            for (int reg = 0; reg < 4; ++reg) {
                int node = n0 + quad * 4 + reg;
                float rv = sigf(aRZ0[reg]);
                float zv = sigf(aRZ1[reg]);
                float nv = tanhfast(fmaf(rv, aHN[reg], aIN[reg]));
                size_t off = (size_t)node * HH + c;
                float ho = h[off];
                float hnew = fmaf(zv, ho - nv, nv);   // (1-z)n + z h
                h[off] = hnew;
                hb[off] = tobf(hnew);
            }
        }
    }
}

// out[i] = sigmoid(dot(h[idx[i]], W_lin) + b_lin)
__global__ __launch_bounds__(256) void k_readout(const float* __restrict__ h,
                                                 const int* __restrict__ idx,
                                                 const float* __restrict__ Wl,
                                                 const float* __restrict__ bl,
                                                 float* __restrict__ out, int B) {
    int gid = blockIdx.x * 256 + threadIdx.x;
    int i = gid >> 6, lane = gid & 63;
    if (i >= B) return;
    int n = idx[i];
    float v = h[(size_t)n * HH + lane] * Wl[lane];
#pragma unroll
    for (int off = 32; off > 0; off >>= 1) v += __shfl_xor(v, off, 64);
    if (lane == 0) out[i] = sigf(v + bl[0]);
}

extern "C" void kernel_launch(void* const* d_in, const int* in_sizes, int n_in,
                              void* d_out, int out_size, void* d_ws, size_t ws_size,
                              hipStream_t stream) {
    const float* x     = (const float*)d_in[0];
    const int*   ei    = (const int*)d_in[1];
    const int*   idx   = (const int*)d_in[2];
    const float* W_red = (const float*)d_in[3];
    const float* b_red = (const float*)d_in[4];
    const float* W_g   = (const float*)d_in[5];
    const float* w_ih  = (const float*)d_in[6];
    const float* w_hh  = (const float*)d_in[7];
    const float* b_ih  = (const float*)d_in[8];
    const float* b_hh  = (const float*)d_in[9];
    const float* W_lin = (const float*)d_in[10];
    const float* b_lin = (const float*)d_in[11];
    float* out = (float*)d_out;
    const int E = in_sizes[1] / 2;
    const int B = in_sizes[2];
    const int* src = ei;
    const int* dst = ei + E;

    float*          h   = (float*)d_ws;                          // [NN,64] fp32
    unsigned short* hb  = (unsigned short*)(h + (size_t)NN * HH);
    unsigned short* Sb  = hb + (size_t)NN * HH;
    unsigned short* Wcp = Sb + (size_t)NN * HH;
    unsigned short* Whp = Wcp + (size_t)NSTEP * 12288;
    int*            cur = (int*)(Whp + 12288);
    int*            srt = cur + NN;
    int*            bsum = srt + E;                               // [NB]

    // ---- CSR build (counting sort by dst, parallel scan) ----
    hipMemsetAsync(cur, 0, NN * sizeof(int), stream);
    k_hist<<<(E + 255) / 256, 256, 0, stream>>>(dst, cur, E);
    k_scan1<<<NB, 256, 0, stream>>>(cur, bsum);
    k_scan2<<<1, 512, 0, stream>>>(bsum);
    k_scan3<<<NB, 256, 0, stream>>>(cur, bsum);
    k_place<<<(E + 255) / 256, 256, 0, stream>>>(src, dst, cur, srt, E);

    // ---- node init + packed weights ----
    k_reduce<<<NN / 16, 256, 0, stream>>>(x, W_red, b_red, h, hb);
    k_wc<<<(NSTEP * 64 * 192 + 255) / 256, 256, 0, stream>>>(W_g, w_ih, Wcp);
    k_whp<<<(192 * 64 + 255) / 256, 256, 0, stream>>>(w_hh, Whp);

    // ---- 8 propagation steps ----
    for (int t = 0; t < NSTEP; ++t) {
        k_aggr<<<(NN / 2 * 64 + 255) / 256, 256, 0, stream>>>(hb, cur, srt, Sb);
        k_gru<<<782, 256, 0, stream>>>(Sb, h, hb, Wcp + (size_t)t * 12288, Whp,
                                       b_ih, b_hh);
    }

    k_readout<<<(B * 64 + 255) / 256, 256, 0, stream>>>(h, idx, W_lin, b_lin, out, B);
}

// Round 9
// 699.670 us; speedup vs baseline: 3.3076x; 1.0710x over previous
//
#include <hip/hip_runtime.h>
#include <hip/hip_bf16.h>

#define NN 100000
#define HH 64
#define AN 92
#define NSTEP 8
#define NGRP 6250          // NN / 16, exact
#define NB 391             // ceil(NN / 256)
#define RB 1250            // k_reduce persistent blocks (5 groups each)

typedef float f4v __attribute__((ext_vector_type(4)));
typedef short s8v __attribute__((ext_vector_type(8)));

__device__ __forceinline__ float sigf(float x) { return 1.0f / (1.0f + __expf(-x)); }
// tanh(x) = 1 - 2/(1+e^{2x}); saturates correctly, no NaN.
__device__ __forceinline__ float tanhfast(float x) { return 1.0f - 2.0f / (1.0f + __expf(2.0f * x)); }

__device__ __forceinline__ unsigned short tobf(float x) {
    __hip_bfloat16 b = __float2bfloat16(x);   // RNE
    return __builtin_bit_cast(unsigned short, b);
}
__device__ __forceinline__ float frombf(unsigned short u) {
    return __int_as_float(((unsigned)u) << 16);
}

// h = x @ W_red + b. Persistent blocks: W staged to LDS ONCE per block
// (R8 restaged 23.5 KB per 16-node block = 6250x); x tile per group.
// Arithmetic identical to R8 -> bit-identical h.
__global__ __launch_bounds__(256) void k_reduce(const float* __restrict__ x,
                                                const float* __restrict__ W,
                                                const float* __restrict__ b,
                                                float* __restrict__ h,
                                                unsigned short* __restrict__ hb) {
    __shared__ float xl[16][96];      // k padded to 96, pads zeroed once
    __shared__ float wl[96 * 64];     // wl[k*64+j] = W[k][j]; k=92..95 zeroed
    int tid = threadIdx.x;
    for (int i = tid; i < AN * 64; i += 256) wl[i] = W[i];
    wl[AN * 64 + tid] = 0.f;                       // zero k=92..95 (4*64=256)
    if (tid < 64) xl[tid >> 2][AN + (tid & 3)] = 0.f;   // zero x pads (persist)
    int lane = tid & 63, wave = tid >> 6;
    float bj = b[lane];

    for (int g = blockIdx.x; g < NGRP; g += RB) {
        int n0 = g * 16;
        __syncthreads();   // xl from previous group fully consumed
        for (int i = tid; i < 16 * AN; i += 256)
            xl[i / AN][i % AN] = x[(size_t)n0 * AN + i];
        __syncthreads();
        float a[4];
#pragma unroll
        for (int u = 0; u < 4; ++u) a[u] = bj;
#pragma unroll
        for (int k4 = 0; k4 < 96; k4 += 4) {
            float4 xv[4];
#pragma unroll
            for (int u = 0; u < 4; ++u) xv[u] = *(const float4*)&xl[wave * 4 + u][k4];
#pragma unroll
            for (int kk = 0; kk < 4; ++kk) {
                float wv = wl[(k4 + kk) * 64 + lane];
                a[0] = fmaf(((const float*)&xv[0])[kk], wv, a[0]);
                a[1] = fmaf(((const float*)&xv[1])[kk], wv, a[1]);
                a[2] = fmaf(((const float*)&xv[2])[kk], wv, a[2]);
                a[3] = fmaf(((const float*)&xv[3])[kk], wv, a[3]);
            }
        }
#pragma unroll
        for (int u = 0; u < 4; ++u) {
            int n = n0 + wave * 4 + u;
            h[(size_t)n * HH + lane] = a[u];
            hb[(size_t)n * HH + lane] = tobf(a[u]);
        }
    }
}

// Packed B-fragment position for mfma_f32_16x16x32_bf16:
// element B[k][r] lives at ((T*2+kh)*64 + lane)*8 + j,
// T=r>>4, kh=k>>5, lane=((k>>3)&3)*16 + (r&15), j=k&7.
__device__ __forceinline__ int packpos(int k, int r) {
    int T = r >> 4, kh = k >> 5;
    int lane = ((k >> 3) & 3) * 16 + (r & 15);
    int j = k & 7;
    return ((T * 2 + kh) * 64 + lane) * 8 + j;
}

// Wc[t][k][r] = sum_q W_g[t][k][q] * w_ih[r][q], bf16 in packed B-frag order.
__global__ __launch_bounds__(256) void k_wc(const float* __restrict__ Wg,
                                            const float* __restrict__ w_ih,
                                            unsigned short* __restrict__ Wcp) {
    __shared__ float wl[192 * 65];
    for (int i = threadIdx.x; i < 192 * 64; i += 256) {
        int r = i >> 6, q = i & 63;
        wl[r * 65 + q] = w_ih[i];
    }
    __syncthreads();
    int gid = blockIdx.x * 256 + threadIdx.x;
    if (gid >= NSTEP * 64 * 192) return;
    int r = gid % 192;
    int k = (gid / 192) & 63;
    int t = gid / (192 * 64);
    const float* wg = Wg + t * 4096 + k * 64;
    float acc = 0.f;
#pragma unroll
    for (int q = 0; q < 64; ++q) acc = fmaf(wg[q], wl[r * 65 + q], acc);
    Wcp[t * 12288 + packpos(k, r)] = tobf(acc);
}

// Whp packed: B[k][r] = w_hh[r][k]  (for gh = h @ w_hh^T)
__global__ __launch_bounds__(256) void k_whp(const float* __restrict__ w_hh,
                                             unsigned short* __restrict__ Whp) {
    int gid = blockIdx.x * 256 + threadIdx.x;
    if (gid >= 192 * 64) return;
    int r = gid >> 6, k = gid & 63;
    Whp[packpos(k, r)] = tobf(w_hh[r * 64 + k]);
}

// cur[dst[e]]++
__global__ __launch_bounds__(256) void k_hist(const int* __restrict__ dst, int* __restrict__ cur, int E) {
    int e = blockIdx.x * 256 + threadIdx.x;
    if (e >= E) return;
    atomicAdd(cur + dst[e], 1);
}

// ---- parallel 3-phase exclusive scan of cur[0..NN) ----
__global__ __launch_bounds__(256) void k_scan1(const int* __restrict__ cur, int* __restrict__ bsum) {
    __shared__ int ws[4];
    int gid = blockIdx.x * 256 + threadIdx.x;
    int lane = threadIdx.x & 63, wave = threadIdx.x >> 6;
    int v = (gid < NN) ? cur[gid] : 0;
#pragma unroll
    for (int off = 32; off > 0; off >>= 1) v += __shfl_xor(v, off, 64);
    if (lane == 0) ws[wave] = v;
    __syncthreads();
    if (threadIdx.x == 0) bsum[blockIdx.x] = ws[0] + ws[1] + ws[2] + ws[3];
}

__global__ __launch_bounds__(512) void k_scan2(int* __restrict__ bsum) {
    __shared__ int s[512];
    int t = threadIdx.x;
    int v = (t < NB) ? bsum[t] : 0;
    s[t] = v;
    __syncthreads();
    for (int off = 1; off < 512; off <<= 1) {
        int w = (t >= off) ? s[t - off] : 0;
        __syncthreads();
        s[t] += w;
        __syncthreads();
    }
    if (t < NB) bsum[t] = s[t] - v;   // exclusive
}

__global__ __launch_bounds__(256) void k_scan3(int* __restrict__ cur, const int* __restrict__ bsum) {
    __shared__ int ws[4];
    int gid = blockIdx.x * 256 + threadIdx.x;
    int lane = threadIdx.x & 63, wave = threadIdx.x >> 6;
    int orig = (gid < NN) ? cur[gid] : 0;
    int v = orig;
#pragma unroll
    for (int off = 1; off < 64; off <<= 1) {
        int w = __shfl_up(v, off, 64);
        if (lane >= off) v += w;
    }
    if (lane == 63) ws[wave] = v;
    __syncthreads();
    int woff = 0;
    for (int w = 0; w < 4; ++w) woff += (w < wave) ? ws[w] : 0;
    if (gid < NN) cur[gid] = v - orig + woff + bsum[blockIdx.x];
}

// srt[cur[dst[e]]++] = src[e]   (after: cur[n] = end offset of segment n)
__global__ __launch_bounds__(256) void k_place(const int* __restrict__ src,
                                               const int* __restrict__ dst,
                                               int* __restrict__ cur,
                                               int* __restrict__ srt, int E) {
    int e = blockIdx.x * 256 + threadIdx.x;
    if (e >= E) return;
    int pos = atomicAdd(cur + dst[e], 1);
    srt[pos] = src[e];
}

// Sb[n][:] = bf16( sum over in-edges of hb[src][:] ).
// 2 nodes per wave (half-wave = full 128B row). Masked 8-deep unroll:
// ALWAYS 8 independent row-gathers in flight; no serial tail (Poisson(8)
// degrees made R8's 4-unroll+scalar-tail latency-serial).
__global__ __launch_bounds__(256) void k_aggr(const unsigned short* __restrict__ hb,
                                              const int* __restrict__ cur,
                                              const int* __restrict__ srt,
                                              unsigned short* __restrict__ Sb) {
    int gid = blockIdx.x * 256 + threadIdx.x;
    int wid = gid >> 6;
    int lane = threadIdx.x & 63;
    int half = lane >> 5;
    int ci = lane & 31;
    int n = wid * 2 + half;
    if (n >= NN) return;
    int st = (n == 0) ? 0 : cur[n - 1];
    int en = cur[n];
    float aa[8], bb[8];
#pragma unroll
    for (int i = 0; i < 8; ++i) { aa[i] = 0.f; bb[i] = 0.f; }
    for (int j = st; j < en; j += 8) {
        unsigned u[8];
#pragma unroll
        for (int i = 0; i < 8; ++i) {
            int jj = j + i;
            int sidx = srt[min(jj, en - 1)];          // clamped: always valid
            unsigned uu = *(const unsigned*)(hb + (size_t)sidx * HH + ci * 2);
            u[i] = (jj < en) ? uu : 0u;               // mask dead lanes (bf16 0 == 0x0)
        }
#pragma unroll
        for (int i = 0; i < 8; ++i) {
            aa[i] += frombf((unsigned short)u[i]);
            bb[i] += frombf((unsigned short)(u[i] >> 16));
        }
    }
    float A = ((aa[0] + aa[1]) + (aa[2] + aa[3])) + ((aa[4] + aa[5]) + (aa[6] + aa[7]));
    float B = ((bb[0] + bb[1]) + (bb[2] + bb[3])) + ((bb[4] + bb[5]) + (bb[6] + bb[7]));
    unsigned o = (unsigned)tobf(A) | ((unsigned)tobf(B) << 16);
    *(unsigned*)(Sb + (size_t)n * HH + ci * 2) = o;
}

// convert 8 consecutive fp32 -> bf16x8 fragment
__device__ __forceinline__ s8v cvt8(const float* __restrict__ p) {
    s8v r;
#pragma unroll
    for (int i = 0; i < 8; ++i) r[i] = (short)tobf(p[i]);
    return r;
}

// MFMA GRU: h(inplace fp32) = GRU(Sb, h); also writes bf16 shadow hb.
// __launch_bounds__(256) ONLY — (256,3) caused allocator spills (R6/R7).
__global__ __launch_bounds__(256) void k_gru(const unsigned short* __restrict__ Sb,
                                             float* __restrict__ h,
                                             unsigned short* __restrict__ hb,
                                             const unsigned short* __restrict__ Wcp_t,
                                             const unsigned short* __restrict__ Whp,
                                             const float* __restrict__ b_ih,
                                             const float* __restrict__ b_hh) {
    __shared__ unsigned short wiL[12288];   // 24 KB
    __shared__ unsigned short whL[12288];   // 24 KB
    for (int i = threadIdx.x; i < 12288 / 8; i += 256) {
        ((ulonglong2*)wiL)[i] = ((const ulonglong2*)Wcp_t)[i];
        ((ulonglong2*)whL)[i] = ((const ulonglong2*)Whp)[i];
    }
    __syncthreads();
    const s8v* wiB = (const s8v*)wiL;
    const s8v* whB = (const s8v*)whL;

    int lane = threadIdx.x & 63;
    int wave = threadIdx.x >> 6;
    int quad = lane >> 4, nidx = lane & 15;
    int fwid = blockIdx.x * 4 + wave;
    int tot = gridDim.x * 4;

    float brz[4], bzz[4], bin[4], bhn[4];
#pragma unroll
    for (int t = 0; t < 4; ++t) {
        int c = t * 16 + nidx;
        brz[t] = b_ih[c] + b_hh[c];
        bzz[t] = b_ih[64 + c] + b_hh[64 + c];
        bin[t] = b_ih[128 + c];
        bhn[t] = b_hh[128 + c];
    }

    for (int g = fwid; g < NGRP; g += tot) {
        int n0 = g * 16;
        size_t rowoff = (size_t)(n0 + nidx) * HH + quad * 8;
        s8v aS0 = *(const s8v*)(Sb + rowoff);
        s8v aS1 = *(const s8v*)(Sb + rowoff + 32);
        s8v aH0 = cvt8(h + rowoff);
        s8v aH1 = cvt8(h + rowoff + 32);

#pragma unroll
        for (int t = 0; t < 4; ++t) {
            f4v aRZ0 = {brz[t], brz[t], brz[t], brz[t]};
            f4v aRZ1 = {bzz[t], bzz[t], bzz[t], bzz[t]};
            f4v aIN  = {bin[t], bin[t], bin[t], bin[t]};
            f4v aHN  = {bhn[t], bhn[t], bhn[t], bhn[t]};
            aRZ0 = __builtin_amdgcn_mfma_f32_16x16x32_bf16(aS0, wiB[(t * 2 + 0) * 64 + lane], aRZ0, 0, 0, 0);
            aRZ0 = __builtin_amdgcn_mfma_f32_16x16x32_bf16(aS1, wiB[(t * 2 + 1) * 64 + lane], aRZ0, 0, 0, 0);
            aRZ0 = __builtin_amdgcn_mfma_f32_16x16x32_bf16(aH0, whB[(t * 2 + 0) * 64 + lane], aRZ0, 0, 0, 0);
            aRZ0 = __builtin_amdgcn_mfma_f32_16x16x32_bf16(aH1, whB[(t * 2 + 1) * 64 + lane], aRZ0, 0, 0, 0);
            int tz = t + 4;
            aRZ1 = __builtin_amdgcn_mfma_f32_16x16x32_bf16(aS0, wiB[(tz * 2 + 0) * 64 + lane], aRZ1, 0, 0, 0);
            aRZ1 = __builtin_amdgcn_mfma_f32_16x16x32_bf16(aS1, wiB[(tz * 2 + 1) * 64 + lane], aRZ1, 0, 0, 0);
            aRZ1 = __builtin_amdgcn_mfma_f32_16x16x32_bf16(aH0, whB[(tz * 2 + 0) * 64 + lane], aRZ1, 0, 0, 0);
            aRZ1 = __builtin_amdgcn_mfma_f32_16x16x32_bf16(aH1, whB[(tz * 2 + 1) * 64 + lane], aRZ1, 0, 0, 0);
            int tn = t + 8;
            aIN = __builtin_amdgcn_mfma_f32_16x16x32_bf16(aS0, wiB[(tn * 2 + 0) * 64 + lane], aIN, 0, 0, 0);
            aIN = __builtin_amdgcn_mfma_f32_16x16x32_bf16(aS1, wiB[(tn * 2 + 1) * 64 + lane], aIN, 0, 0, 0);
            aHN = __builtin_amdgcn_mfma_f32_16x16x32_bf16(aH0, whB[(tn * 2 + 0) * 64 + lane], aHN, 0, 0, 0);
            aHN = __builtin_amdgcn_mfma_f32_16x16x32_bf16(aH1, whB[(tn * 2 + 1) * 64 + lane], aHN, 0, 0, 0);
            int c = t * 16 + nidx;
#pragma unroll
            for (int reg = 0; reg < 4; ++reg) {
                int node = n0 + quad * 4 + reg;
                float rv = sigf(aRZ0[reg]);
                float zv = sigf(aRZ1[reg]);
                float nv = tanhfast(fmaf(rv, aHN[reg], aIN[reg]));
                size_t off = (size_t)node * HH + c;
                float ho = h[off];
                float hnew = fmaf(zv, ho - nv, nv);   // (1-z)n + z h
                h[off] = hnew;
                hb[off] = tobf(hnew);
            }
        }
    }
}

// out[i] = sigmoid(dot(h[idx[i]], W_lin) + b_lin)
__global__ __launch_bounds__(256) void k_readout(const float* __restrict__ h,
                                                 const int* __restrict__ idx,
                                                 const float* __restrict__ Wl,
                                                 const float* __restrict__ bl,
                                                 float* __restrict__ out, int B) {
    int gid = blockIdx.x * 256 + threadIdx.x;
    int i = gid >> 6, lane = gid & 63;
    if (i >= B) return;
    int n = idx[i];
    float v = h[(size_t)n * HH + lane] * Wl[lane];
#pragma unroll
    for (int off = 32; off > 0; off >>= 1) v += __shfl_xor(v, off, 64);
    if (lane == 0) out[i] = sigf(v + bl[0]);
}

extern "C" void kernel_launch(void* const* d_in, const int* in_sizes, int n_in,
                              void* d_out, int out_size, void* d_ws, size_t ws_size,
                              hipStream_t stream) {
    const float* x     = (const float*)d_in[0];
    const int*   ei    = (const int*)d_in[1];
    const int*   idx   = (const int*)d_in[2];
    const float* W_red = (const float*)d_in[3];
    const float* b_red = (const float*)d_in[4];
    const float* W_g   = (const float*)d_in[5];
    const float* w_ih  = (const float*)d_in[6];
    const float* w_hh  = (const float*)d_in[7];
    const float* b_ih  = (const float*)d_in[8];
    const float* b_hh  = (const float*)d_in[9];
    const float* W_lin = (const float*)d_in[10];
    const float* b_lin = (const float*)d_in[11];
    float* out = (float*)d_out;
    const int E = in_sizes[1] / 2;
    const int B = in_sizes[2];
    const int* src = ei;
    const int* dst = ei + E;

    float*          h   = (float*)d_ws;                          // [NN,64] fp32
    unsigned short* hb  = (unsigned short*)(h + (size_t)NN * HH);
    unsigned short* Sb  = hb + (size_t)NN * HH;
    unsigned short* Wcp = Sb + (size_t)NN * HH;
    unsigned short* Whp = Wcp + (size_t)NSTEP * 12288;
    int*            cur = (int*)(Whp + 12288);
    int*            srt = cur + NN;
    int*            bsum = srt + E;                               // [NB]

    // ---- CSR build (counting sort by dst, parallel scan) ----
    hipMemsetAsync(cur, 0, NN * sizeof(int), stream);
    k_hist<<<(E + 255) / 256, 256, 0, stream>>>(dst, cur, E);
    k_scan1<<<NB, 256, 0, stream>>>(cur, bsum);
    k_scan2<<<1, 512, 0, stream>>>(bsum);
    k_scan3<<<NB, 256, 0, stream>>>(cur, bsum);
    k_place<<<(E + 255) / 256, 256, 0, stream>>>(src, dst, cur, srt, E);

    // ---- node init + packed weights ----
    k_reduce<<<RB, 256, 0, stream>>>(x, W_red, b_red, h, hb);
    k_wc<<<(NSTEP * 64 * 192 + 255) / 256, 256, 0, stream>>>(W_g, w_ih, Wcp);
    k_whp<<<(192 * 64 + 255) / 256, 256, 0, stream>>>(w_hh, Whp);

    // ---- 8 propagation steps ----
    for (int t = 0; t < NSTEP; ++t) {
        k_aggr<<<(NN / 2 * 64 + 255) / 256, 256, 0, stream>>>(hb, cur, srt, Sb);
        k_gru<<<782, 256, 0, stream>>>(Sb, h, hb, Wcp + (size_t)t * 12288, Whp,
                                       b_ih, b_hh);
    }

    k_readout<<<(B * 64 + 255) / 256, 256, 0, stream>>>(h, idx, W_lin, b_lin, out, B);
}